// Round 8
// baseline (1065.703 us; speedup 1.0000x reference)
//
#include <hip/hip_runtime.h>

#define N_G   15135
#define E_N   242160
#define BSZ   8
#define K_TOP 7568
#define NH    128
#define NBIN  65536
#define SUFS  65600

typedef float f4v __attribute__((ext_vector_type(4)));

// ---------------- utility ----------------
__global__ void zero_kernel(int* __restrict__ p, int n) {
  int i = blockIdx.x * 1024 + threadIdx.x;
  if (i < n) p[i] = 0;
}

__global__ void count_kernel(const int* __restrict__ ei, int* __restrict__ cnt) {
  int e = blockIdx.x * 256 + threadIdx.x;
  if (e < E_N) atomicAdd(&cnt[ei[E_N + e]], 1);
}

__global__ __launch_bounds__(1024) void scan_kernel(const int* __restrict__ cnt,
                                                    int* __restrict__ rowstart,
                                                    float* __restrict__ dinv,
                                                    int* __restrict__ gctr,
                                                    const float* __restrict__ topk_w,
                                                    float* __restrict__ scal) {
  __shared__ int buf[1024];
  __shared__ int base;
  int tid = threadIdx.x;
  int i = blockIdx.x * 1024 + tid;
  int v = (i < N_G) ? cnt[i] : 0;
  if (i < N_G) dinv[i] = 1.0f / sqrtf((float)(v + 1));
  buf[tid] = v;
  __syncthreads();
  for (int s = 1; s < 1024; s <<= 1) {
    int t = (tid >= s) ? buf[tid - s] : 0;
    __syncthreads();
    buf[tid] += t;
    __syncthreads();
  }
  if (tid == 1023) base = atomicAdd(gctr, buf[1023]);
  __syncthreads();
  if (i < N_G) rowstart[i] = base + buf[tid] - v;
  if (blockIdx.x == 0) {
    __shared__ float fbuf[512];
    if (tid < 512) {
      float w = (tid < 384) ? topk_w[tid] : 0.f;
      fbuf[tid] = w * w;
    }
    __syncthreads();
    for (int s = 256; s > 0; s >>= 1) {
      if (tid < s) fbuf[tid] += fbuf[tid + s];
      __syncthreads();
    }
    if (tid == 0) scal[0] = 1.0f / sqrtf(fbuf[0]);
  }
}

__global__ void fill_kernel(const int* __restrict__ ei, const int* __restrict__ rowstart,
                            int* __restrict__ fillc, int* __restrict__ csr) {
  int e = blockIdx.x * 256 + threadIdx.x;
  if (e < E_N) {
    int s = ei[e], d = ei[E_N + e];
    int pos = rowstart[d] + atomicAdd(&fillc[d], 1);
    csr[pos] = s;
  }
}

// ---------------- dense matmul: out[M][128] = A[M][CIN] @ W[CIN][128] (+bias,relu) ----
template<int CIN, bool BR>
__global__ __launch_bounds__(256, 6) void mm_kernel(const float* __restrict__ A,
                                                    const float* __restrict__ W,
                                                    const float* __restrict__ bias,
                                                    float* __restrict__ out, int M) {
  __shared__ float Bst[32][132];
  __shared__ float Ast2[32][68];
  int tid = threadIdx.x;
  int rb0 = blockIdx.x * 64;
  int c0 = (tid & 31) * 4;
  int r0 = (tid >> 5) * 8;
  float acc[8][4];
#pragma unroll
  for (int i = 0; i < 8; i++)
#pragma unroll
    for (int j = 0; j < 4; j++) acc[i][j] = 0.f;

  for (int k0 = 0; k0 < CIN; k0 += 32) {
    {
      int koff = (tid & 7) * 4;
      int row = tid >> 3;
#pragma unroll
      for (int p = 0; p < 2; ++p) {
        int r = row + p * 32;
        int grow = rb0 + r;
        f4v v = {0.f, 0.f, 0.f, 0.f};
        if (grow < M) v = __builtin_nontemporal_load((const f4v*)(A + (size_t)grow * CIN + k0 + koff));
        Ast2[koff + 0][r] = v.x; Ast2[koff + 1][r] = v.y;
        Ast2[koff + 2][r] = v.z; Ast2[koff + 3][r] = v.w;
      }
    }
    {
      int cc = (tid & 31) * 4;
      int kr = tid >> 5;
#pragma unroll
      for (int p = 0; p < 4; ++p) {
        int k = kr + p * 8;
        *(float4*)&Bst[k][cc] = *(const float4*)(W + (size_t)(k0 + k) * NH + cc);
      }
    }
    __syncthreads();
#pragma unroll 4
    for (int kk = 0; kk < 32; ++kk) {
      float a[8], b[4];
      *(float4*)&a[0] = *(const float4*)&Ast2[kk][r0];
      *(float4*)&a[4] = *(const float4*)&Ast2[kk][r0 + 4];
      *(float4*)&b[0] = *(const float4*)&Bst[kk][c0];
#pragma unroll
      for (int i = 0; i < 8; i++)
#pragma unroll
        for (int j = 0; j < 4; j++)
          acc[i][j] = fmaf(a[i], b[j], acc[i][j]);
    }
    __syncthreads();
  }
  float b0 = 0.f, b1 = 0.f, b2 = 0.f, b3 = 0.f;
  if (BR) { b0 = bias[c0]; b1 = bias[c0+1]; b2 = bias[c0+2]; b3 = bias[c0+3]; }
#pragma unroll
  for (int i = 0; i < 8; i++) {
    int row = rb0 + r0 + i;
    if (row < M) {
      f4v v;
      if (BR) {
        v.x = fmaxf(acc[i][0] + b0, 0.f); v.y = fmaxf(acc[i][1] + b1, 0.f);
        v.z = fmaxf(acc[i][2] + b2, 0.f); v.w = fmaxf(acc[i][3] + b3, 0.f);
      } else {
        v.x = acc[i][0]; v.y = acc[i][1]; v.z = acc[i][2]; v.w = acc[i][3];
      }
      __builtin_nontemporal_store(v, (f4v*)(out + (size_t)row * NH + c0));
    }
  }
}

// ---------------- sparse aggregation, channel-quarter (32 ch), 2-edge parity lanes ----
// One wave per dst row. eh=lane>>5 picks edge parity; ch = q*32 + (lane&31).
// Gather slice per (batch,quarter) = 15135*128B = 1.94 MB < 4 MiB XCD L2; streams are NT.
template<int CH, bool BR>
__global__ __launch_bounds__(256) void agg_q_kernel(const float* __restrict__ src,
                                                    const int* __restrict__ csr,
                                                    const int* __restrict__ rowstart,
                                                    const int* __restrict__ cnt,
                                                    const float* __restrict__ dinv,
                                                    const float* __restrict__ bias,
                                                    float* __restrict__ dst, int q) {
  int b = blockIdx.x & 7;
  int chunk = blockIdx.x >> 3;
  int wave = threadIdx.x >> 6, lane = threadIdx.x & 63;
  int d = chunk * 4 + wave;
  if (d >= N_G) return;
  d = __builtin_amdgcn_readfirstlane(d);
  int eh = lane >> 5;
  int ch = q * 32 + (lane & 31);
  const float* sb = src + (size_t)b * N_G * CH;
  float dv = dinv[d];
  int e0 = rowstart[d];
  int n = cnt[d];
  const int* ce = csr + e0;
  float acc0 = eh ? 0.f : dv * sb[(size_t)d * CH + ch];
  float acc1 = 0.f, acc2 = 0.f, acc3 = 0.f;
  int l = 0;
  for (; l + 16 <= n; l += 16) {
    int p0 = eh ? ce[l+1]  : ce[l+0];
    int p1 = eh ? ce[l+3]  : ce[l+2];
    int p2 = eh ? ce[l+5]  : ce[l+4];
    int p3 = eh ? ce[l+7]  : ce[l+6];
    int p4 = eh ? ce[l+9]  : ce[l+8];
    int p5 = eh ? ce[l+11] : ce[l+10];
    int p6 = eh ? ce[l+13] : ce[l+12];
    int p7 = eh ? ce[l+15] : ce[l+14];
    float w0 = dinv[p0], w1 = dinv[p1], w2 = dinv[p2], w3 = dinv[p3];
    float w4 = dinv[p4], w5 = dinv[p5], w6 = dinv[p6], w7 = dinv[p7];
    float v0 = sb[(size_t)p0 * CH + ch];
    float v1 = sb[(size_t)p1 * CH + ch];
    float v2 = sb[(size_t)p2 * CH + ch];
    float v3 = sb[(size_t)p3 * CH + ch];
    float v4 = sb[(size_t)p4 * CH + ch];
    float v5 = sb[(size_t)p5 * CH + ch];
    float v6 = sb[(size_t)p6 * CH + ch];
    float v7 = sb[(size_t)p7 * CH + ch];
    acc0 = fmaf(w0, v0, acc0); acc1 = fmaf(w1, v1, acc1);
    acc2 = fmaf(w2, v2, acc2); acc3 = fmaf(w3, v3, acc3);
    acc0 = fmaf(w4, v4, acc0); acc1 = fmaf(w5, v5, acc1);
    acc2 = fmaf(w6, v6, acc2); acc3 = fmaf(w7, v7, acc3);
  }
  for (; l + 2 <= n; l += 2) {
    int p = eh ? ce[l+1] : ce[l+0];
    acc0 = fmaf(dinv[p], sb[(size_t)p * CH + ch], acc0);
  }
  if (l < n) {
    int s = ce[l];
    if (!eh) acc0 = fmaf(dinv[s], sb[(size_t)s * CH + ch], acc0);
  }
  float s = (acc0 + acc1) + (acc2 + acc3);
  s += __shfl_xor(s, 32);
  if (eh == 0) {
    float r = BR ? fmaxf(fmaf(dv, s, bias[ch]), 0.f) : dv * s;
    __builtin_nontemporal_store(r, &dst[((size_t)b * N_G + d) * CH + ch]);
  }
}

// ---------------- layer-3 quarter-agg fused with partial score/fc dots ----------------
__global__ __launch_bounds__(256) void agg_score_q_kernel(const float* __restrict__ hw,
                                                          const int* __restrict__ csr,
                                                          const int* __restrict__ rowstart,
                                                          const int* __restrict__ cnt,
                                                          const float* __restrict__ dinv,
                                                          const float* __restrict__ bias,
                                                          const float* __restrict__ h1,
                                                          const float* __restrict__ h2,
                                                          const float* __restrict__ topk_w,
                                                          const float* __restrict__ fcW,
                                                          float* __restrict__ pd1,
                                                          float* __restrict__ pd2, int q) {
  int b = blockIdx.x & 7;
  int chunk = blockIdx.x >> 3;
  int wave = threadIdx.x >> 6, lane = threadIdx.x & 63;
  int d = chunk * 4 + wave;
  if (d >= N_G) return;
  d = __builtin_amdgcn_readfirstlane(d);
  int eh = lane >> 5;
  int ch = q * 32 + (lane & 31);
  const float* sb = hw + (size_t)b * N_G * NH;
  float dv = dinv[d];
  int e0 = rowstart[d];
  int n = cnt[d];
  const int* ce = csr + e0;
  float acc0 = eh ? 0.f : dv * sb[(size_t)d * NH + ch];
  float acc1 = 0.f, acc2 = 0.f, acc3 = 0.f;
  int l = 0;
  for (; l + 16 <= n; l += 16) {
    int p0 = eh ? ce[l+1]  : ce[l+0];
    int p1 = eh ? ce[l+3]  : ce[l+2];
    int p2 = eh ? ce[l+5]  : ce[l+4];
    int p3 = eh ? ce[l+7]  : ce[l+6];
    int p4 = eh ? ce[l+9]  : ce[l+8];
    int p5 = eh ? ce[l+11] : ce[l+10];
    int p6 = eh ? ce[l+13] : ce[l+12];
    int p7 = eh ? ce[l+15] : ce[l+14];
    float w0 = dinv[p0], w1 = dinv[p1], w2 = dinv[p2], w3 = dinv[p3];
    float w4 = dinv[p4], w5 = dinv[p5], w6 = dinv[p6], w7 = dinv[p7];
    float v0 = sb[(size_t)p0 * NH + ch];
    float v1 = sb[(size_t)p1 * NH + ch];
    float v2 = sb[(size_t)p2 * NH + ch];
    float v3 = sb[(size_t)p3 * NH + ch];
    float v4 = sb[(size_t)p4 * NH + ch];
    float v5 = sb[(size_t)p5 * NH + ch];
    float v6 = sb[(size_t)p6 * NH + ch];
    float v7 = sb[(size_t)p7 * NH + ch];
    acc0 = fmaf(w0, v0, acc0); acc1 = fmaf(w1, v1, acc1);
    acc2 = fmaf(w2, v2, acc2); acc3 = fmaf(w3, v3, acc3);
    acc0 = fmaf(w4, v4, acc0); acc1 = fmaf(w5, v5, acc1);
    acc2 = fmaf(w6, v6, acc2); acc3 = fmaf(w7, v7, acc3);
  }
  for (; l + 2 <= n; l += 2) {
    int p = eh ? ce[l+1] : ce[l+0];
    acc0 = fmaf(dinv[p], sb[(size_t)p * NH + ch], acc0);
  }
  if (l < n) {
    int s = ce[l];
    if (!eh) acc0 = fmaf(dinv[s], sb[(size_t)s * NH + ch], acc0);
  }
  float s = (acc0 + acc1) + (acc2 + acc3);
  s += __shfl_xor(s, 32);
  if (eh == 0) {
    float r = fmaxf(fmaf(dv, s, bias[ch]), 0.f);
    size_t rbase = ((size_t)b * N_G + d) * NH + ch;
    float u1 = __builtin_nontemporal_load(h1 + rbase);
    float u2 = __builtin_nontemporal_load(h2 + rbase);
    float d1 = u1 * topk_w[ch * 3] + u2 * topk_w[ch * 3 + 1] + r * topk_w[ch * 3 + 2];
    float d2 = u1 * fcW[ch * 3]    + u2 * fcW[ch * 3 + 1]    + r * fcW[ch * 3 + 2];
#pragma unroll
    for (int sh = 16; sh > 0; sh >>= 1) {
      d1 += __shfl_down(d1, sh, 32);
      d2 += __shfl_down(d2, sh, 32);
    }
    if ((lane & 31) == 0) {
      int gw = b * N_G + d;
      pd1[gw * 4 + q] = d1;
      pd2[gw * 4 + q] = d2;
    }
  }
}

// ---------------- combine quarters -> score/key + histogram ----------------
__global__ void combine_kernel(const float* __restrict__ pd1, const float* __restrict__ pd2,
                               const float* __restrict__ scal, float* __restrict__ score,
                               float* __restrict__ d2a, unsigned* __restrict__ keys,
                               int* __restrict__ hist) {
  int b = blockIdx.y;
  int i = blockIdx.x * 256 + threadIdx.x;
  if (i >= N_G) return;
  int gw = b * N_G + i;
  float d1 = (pd1[4*gw] + pd1[4*gw+1]) + (pd1[4*gw+2] + pd1[4*gw+3]);
  float d2 = (pd2[4*gw] + pd2[4*gw+1]) + (pd2[4*gw+2] + pd2[4*gw+3]);
  float sc = tanhf(d1 * scal[0]);
  score[gw] = sc;
  d2a[gw] = d2;
  unsigned u = __float_as_uint(sc);
  unsigned k32 = (u & 0x80000000u) ? ~u : (u | 0x80000000u);
  keys[gw] = k32;
  atomicAdd(&hist[b * NBIN + (int)(k32 >> 16)], 1);
}

// ---------------- per-batch suffix sums over 65536 bins ----------------
__global__ __launch_bounds__(1024) void suffix_kernel(const int* __restrict__ hist,
                                                      int* __restrict__ suf) {
  __shared__ int buf[1024];
  int b = blockIdx.x;
  const int* hb = hist + b * NBIN;
  int* sb = suf + b * SUFS;
  int t = threadIdx.x;
  int base = t * 64;
  int s = 0;
  for (int k = 0; k < 64; ++k) s += hb[base + k];
  buf[t] = s;
  __syncthreads();
  for (int off = 1; off < 1024; off <<= 1) {
    int v = (t + off < 1024) ? buf[t + off] : 0;
    __syncthreads();
    buf[t] += v;
    __syncthreads();
  }
  int acc = buf[t] - s;
  if (t == 0) sb[NBIN] = 0;
  for (int k = 63; k >= 0; --k) {
    acc += hb[base + k];
    sb[base + k] = acc;
  }
}

// ---------------- bucket scatter (consumes hist via atomicSub) ----------------
__global__ void scatter_kernel(const unsigned* __restrict__ keys, int* __restrict__ hist,
                               const int* __restrict__ suf, int2* __restrict__ bucket) {
  int b = blockIdx.y;
  int i = blockIdx.x * 256 + threadIdx.x;
  if (i >= N_G) return;
  unsigned k = keys[b * N_G + i];
  int bin = (int)(k >> 16);
  int old = atomicSub(&hist[b * NBIN + bin], 1);
  int pos = suf[b * SUFS + bin + 1] + old - 1;
  bucket[b * N_G + pos] = make_int2((int)k, i);
}

// ---------------- exact stable-descending rank + z scatter ----------------
__global__ void rank_z_kernel(const unsigned* __restrict__ keys, const int* __restrict__ suf,
                              const int2* __restrict__ bucket, const float* __restrict__ score,
                              const float* __restrict__ d2a, const float* __restrict__ fcb,
                              float* __restrict__ z) {
  int b = blockIdx.y;
  int i = blockIdx.x * 256 + threadIdx.x;
  if (i >= N_G) return;
  int gw = b * N_G + i;
  unsigned k = keys[gw];
  int bin = (int)(k >> 16);
  int lo = suf[b * SUFS + bin + 1];
  int hi = suf[b * SUFS + bin];
  int r = lo;
  const int2* bk = bucket + b * N_G;
  for (int p = lo; p < hi; ++p) {
    int2 e = bk[p];
    unsigned kj = (unsigned)e.x;
    r += (kj > k || (kj == k && e.y < i)) ? 1 : 0;
  }
  if (r < K_TOP) z[b * K_TOP + r] = fmaf(score[gw], d2a[gw], fcb[0]);
}

// ---------------- lin1 ----------------
__global__ __launch_bounds__(256) void lin1_kernel(const float* __restrict__ z,
                                                   const float* __restrict__ W,
                                                   float* __restrict__ hpre) {
  __shared__ float zb[237];
  int b = blockIdx.y, rs = blockIdx.x;
  int r0 = rs * 237;
  int rn = K_TOP - r0; if (rn > 237) rn = 237;
  for (int q = threadIdx.x; q < rn; q += 256) zb[q] = z[b * K_TOP + r0 + q];
  __syncthreads();
  int c = threadIdx.x;
  float a0 = 0.f, a1 = 0.f;
  for (int r = 0; r < rn; ++r) {
    float zz = zb[r];
    const float* wr = W + (size_t)(r0 + r) * 512;
    a0 = fmaf(zz, wr[c], a0);
    a1 = fmaf(zz, wr[c + 256], a1);
  }
  atomicAdd(&hpre[b * 512 + c], a0);
  atomicAdd(&hpre[b * 512 + c + 256], a1);
}

// ---------------- lin2 + log_softmax ----------------
__global__ __launch_bounds__(128) void lin2_kernel(const float* __restrict__ hpre,
                                                   const float* __restrict__ l1b,
                                                   const float* __restrict__ W2,
                                                   const float* __restrict__ l2b,
                                                   float* __restrict__ out) {
  int b = blockIdx.x, tid = threadIdx.x;
  float a0 = 0.f, a1 = 0.f;
  for (int j = tid; j < 512; j += 128) {
    float t = fmaxf(hpre[b * 512 + j] + l1b[j], 0.f);
    a0 = fmaf(t, W2[j * 2 + 0], a0);
    a1 = fmaf(t, W2[j * 2 + 1], a1);
  }
#pragma unroll
  for (int s = 32; s > 0; s >>= 1) {
    a0 += __shfl_down(a0, s);
    a1 += __shfl_down(a1, s);
  }
  __shared__ float red[2][2];
  if ((tid & 63) == 0) { red[tid >> 6][0] = a0; red[tid >> 6][1] = a1; }
  __syncthreads();
  if (tid == 0) {
    float l0 = red[0][0] + red[1][0] + l2b[0];
    float l1 = red[0][1] + red[1][1] + l2b[1];
    float m = fmaxf(l0, l1);
    float lse = m + logf(expf(l0 - m) + expf(l1 - m));
    out[b * 2 + 0] = l0 - lse;
    out[b * 2 + 1] = l1 - lse;
  }
}

extern "C" void kernel_launch(void* const* d_in, const int* in_sizes, int n_in,
                              void* d_out, int out_size, void* d_ws, size_t ws_size,
                              hipStream_t stream) {
  const float* x   = (const float*)d_in[0];
  const int*   ei  = (const int*)d_in[2];
  const float* W1  = (const float*)d_in[3];
  const float* b1  = (const float*)d_in[4];
  const float* W2  = (const float*)d_in[5];
  const float* b2  = (const float*)d_in[6];
  const float* W3  = (const float*)d_in[7];
  const float* b3  = (const float*)d_in[8];
  const float* tkw = (const float*)d_in[9];
  const float* fcW = (const float*)d_in[10];
  const float* fcb = (const float*)d_in[11];
  const float* l1W = (const float*)d_in[12];
  const float* l1b = (const float*)d_in[13];
  const float* l2W = (const float*)d_in[14];
  const float* l2b = (const float*)d_in[15];
  float* out = (float*)d_out;

  char* ws = (char*)d_ws;
  size_t off = 0;
  auto alloc = [&](size_t bytes) {
    char* p = ws + off;
    off += (bytes + 255) & ~(size_t)255;
    return p;
  };
  // zero-init region (contiguous): cnt, fillc, gctr, hpre, hist
  int*   cnt   = (int*)alloc(15136 * 4);
  int*   fillc = (int*)alloc(15136 * 4);
  int*   gctr  = (int*)alloc(256);
  float* hpre  = (float*)alloc(4096 * 4);
  int*   hist  = (int*)alloc((size_t)BSZ * NBIN * 4);
  // --- end zero region ---
  int*   rowstart = (int*)alloc(15136 * 4);
  float* dinv  = (float*)alloc(15136 * 4);
  float* scal  = (float*)alloc(64);
  float* z     = (float*)alloc((size_t)BSZ * K_TOP * 4);
  float* score = (float*)alloc(121088 * 4);
  float* d2a   = (float*)alloc(121088 * 4);
  unsigned* keys = (unsigned*)alloc(121088 * 4);
  int*   suf   = (int*)alloc((size_t)BSZ * SUFS * 4);
  int2*  bucket = (int2*)alloc(121088 * 8);
  float* pd1   = (float*)alloc(121088 * 4 * 4);
  float* pd2   = (float*)alloc(121088 * 4 * 4);
  int*   csr   = (int*)alloc((size_t)E_N * 4);
  float* ax = (float*)alloc((size_t)BSZ * N_G * 64 * 4);
  float* hw = (float*)alloc((size_t)BSZ * N_G * NH * 4);
  float* h1 = (float*)alloc((size_t)BSZ * N_G * NH * 4);
  float* h2 = (float*)alloc((size_t)BSZ * N_G * NH * 4);
  (void)ws_size; (void)in_sizes; (void)n_in; (void)out_size;

  int zero_n = (int)(((char*)rowstart - (char*)cnt) / 4);
  zero_kernel<<<(zero_n + 1023) / 1024, 1024, 0, stream>>>(cnt, zero_n);
  count_kernel<<<(E_N + 255) / 256, 256, 0, stream>>>(ei, cnt);
  scan_kernel<<<(N_G + 1023) / 1024, 1024, 0, stream>>>(cnt, rowstart, dinv, gctr, tkw, scal);
  fill_kernel<<<(E_N + 255) / 256, 256, 0, stream>>>(ei, rowstart, fillc, csr);

  int M = BSZ * N_G;
  dim3 mmg((M + 63) / 64);
  int aggblocks = 8 * ((N_G + 3) / 4);

  // layer 1: agg(x) @ W1  (agg commutes with right-multiply)
  agg_q_kernel<64, false><<<aggblocks, 256, 0, stream>>>(x, csr, rowstart, cnt, dinv, nullptr, ax, 0);
  agg_q_kernel<64, false><<<aggblocks, 256, 0, stream>>>(x, csr, rowstart, cnt, dinv, nullptr, ax, 1);
  mm_kernel<64, true><<<mmg, 256, 0, stream>>>(ax, W1, b1, h1, M);
  // layer 2
  mm_kernel<128, false><<<mmg, 256, 0, stream>>>(h1, W2, nullptr, hw, M);
  for (int q = 0; q < 4; ++q)
    agg_q_kernel<128, true><<<aggblocks, 256, 0, stream>>>(hw, csr, rowstart, cnt, dinv, b2, h2, q);
  // layer 3 fused with score partials
  mm_kernel<128, false><<<mmg, 256, 0, stream>>>(h2, W3, nullptr, hw, M);
  for (int q = 0; q < 4; ++q)
    agg_score_q_kernel<<<aggblocks, 256, 0, stream>>>(hw, csr, rowstart, cnt, dinv, b3,
                                                      h1, h2, tkw, fcW, pd1, pd2, q);

  dim3 ng((N_G + 255) / 256, BSZ);
  combine_kernel<<<ng, 256, 0, stream>>>(pd1, pd2, scal, score, d2a, keys, hist);
  suffix_kernel<<<BSZ, 1024, 0, stream>>>(hist, suf);
  scatter_kernel<<<ng, 256, 0, stream>>>(keys, hist, suf, bucket);
  rank_z_kernel<<<ng, 256, 0, stream>>>(keys, suf, bucket, score, d2a, fcb, z);

  dim3 l1g(32, BSZ);
  lin1_kernel<<<l1g, 256, 0, stream>>>(z, l1W, hpre);
  lin2_kernel<<<BSZ, 128, 0, stream>>>(hpre, l1b, l2W, l2b, out);
}

// Round 9
// 724.917 us; speedup vs baseline: 1.4701x; 1.4701x over previous
//
#include <hip/hip_runtime.h>

#define N_G   15135
#define E_N   242160
#define BSZ   8
#define K_TOP 7568
#define NH    128
#define NBIN  65536
#define SUFS  65600

typedef float f4v __attribute__((ext_vector_type(4)));

// ---------------- utility ----------------
__global__ void zero_kernel(int* __restrict__ p, int n) {
  int i = blockIdx.x * 1024 + threadIdx.x;
  if (i < n) p[i] = 0;
}

__global__ void count_kernel(const int* __restrict__ ei, int* __restrict__ cnt) {
  int e = blockIdx.x * 256 + threadIdx.x;
  if (e < E_N) atomicAdd(&cnt[ei[E_N + e]], 1);
}

__global__ __launch_bounds__(1024) void scan_kernel(const int* __restrict__ cnt,
                                                    int* __restrict__ rowstart,
                                                    float* __restrict__ dinv,
                                                    int* __restrict__ gctr,
                                                    const float* __restrict__ topk_w,
                                                    float* __restrict__ scal) {
  __shared__ int buf[1024];
  __shared__ int base;
  int tid = threadIdx.x;
  int i = blockIdx.x * 1024 + tid;
  int v = (i < N_G) ? cnt[i] : 0;
  if (i < N_G) dinv[i] = 1.0f / sqrtf((float)(v + 1));
  buf[tid] = v;
  __syncthreads();
  for (int s = 1; s < 1024; s <<= 1) {
    int t = (tid >= s) ? buf[tid - s] : 0;
    __syncthreads();
    buf[tid] += t;
    __syncthreads();
  }
  if (tid == 1023) base = atomicAdd(gctr, buf[1023]);
  __syncthreads();
  if (i < N_G) rowstart[i] = base + buf[tid] - v;
  if (blockIdx.x == 0) {
    __shared__ float fbuf[512];
    if (tid < 512) {
      float w = (tid < 384) ? topk_w[tid] : 0.f;
      fbuf[tid] = w * w;
    }
    __syncthreads();
    for (int s = 256; s > 0; s >>= 1) {
      if (tid < s) fbuf[tid] += fbuf[tid + s];
      __syncthreads();
    }
    if (tid == 0) scal[0] = 1.0f / sqrtf(fbuf[0]);
  }
}

__global__ void fill_kernel(const int* __restrict__ ei, const int* __restrict__ rowstart,
                            int* __restrict__ fillc, int* __restrict__ csr) {
  int e = blockIdx.x * 256 + threadIdx.x;
  if (e < E_N) {
    int s = ei[e], d = ei[E_N + e];
    int pos = rowstart[d] + atomicAdd(&fillc[d], 1);
    csr[pos] = s;
  }
}

// ---------------- dense matmul, batch-pinned blocks ----------------
// Grid = 8*237: b=blk&7 -> XCD b (same pinning as agg), so hw lines written by
// batch b land in XCD b's L2 for the immediately-following gather dispatch.
template<int CIN, bool BR>
__global__ __launch_bounds__(256, 6) void mm_kernel(const float* __restrict__ A,
                                                    const float* __restrict__ W,
                                                    const float* __restrict__ bias,
                                                    float* __restrict__ out) {
  __shared__ float Bst[32][132];
  __shared__ float Ast2[32][68];
  int tid = threadIdx.x;
  int b = blockIdx.x & 7;
  int ib = blockIdx.x >> 3;
  int rb0 = b * N_G + ib * 64;       // global row base
  int rmax = N_G - ib * 64;          // valid rows in tile
  int c0 = (tid & 31) * 4;
  int r0 = (tid >> 5) * 8;
  float acc[8][4];
#pragma unroll
  for (int i = 0; i < 8; i++)
#pragma unroll
    for (int j = 0; j < 4; j++) acc[i][j] = 0.f;

  for (int k0 = 0; k0 < CIN; k0 += 32) {
    {
      int koff = (tid & 7) * 4;
      int row = tid >> 3;
#pragma unroll
      for (int p = 0; p < 2; ++p) {
        int r = row + p * 32;
        f4v v = {0.f, 0.f, 0.f, 0.f};
        if (r < rmax) v = __builtin_nontemporal_load((const f4v*)(A + (size_t)(rb0 + r) * CIN + k0 + koff));
        Ast2[koff + 0][r] = v.x; Ast2[koff + 1][r] = v.y;
        Ast2[koff + 2][r] = v.z; Ast2[koff + 3][r] = v.w;
      }
    }
    {
      int cc = (tid & 31) * 4;
      int kr = tid >> 5;
#pragma unroll
      for (int p = 0; p < 4; ++p) {
        int k = kr + p * 8;
        *(float4*)&Bst[k][cc] = *(const float4*)(W + (size_t)(k0 + k) * NH + cc);
      }
    }
    __syncthreads();
#pragma unroll 4
    for (int kk = 0; kk < 32; ++kk) {
      float a[8], bb[4];
      *(float4*)&a[0] = *(const float4*)&Ast2[kk][r0];
      *(float4*)&a[4] = *(const float4*)&Ast2[kk][r0 + 4];
      *(float4*)&bb[0] = *(const float4*)&Bst[kk][c0];
#pragma unroll
      for (int i = 0; i < 8; i++)
#pragma unroll
        for (int j = 0; j < 4; j++)
          acc[i][j] = fmaf(a[i], bb[j], acc[i][j]);
    }
    __syncthreads();
  }
  float b0 = 0.f, b1 = 0.f, b2 = 0.f, b3 = 0.f;
  if (BR) { b0 = bias[c0]; b1 = bias[c0+1]; b2 = bias[c0+2]; b3 = bias[c0+3]; }
#pragma unroll
  for (int i = 0; i < 8; i++) {
    int r = r0 + i;
    if (r < rmax) {
      float4 v;
      if (BR) {
        v.x = fmaxf(acc[i][0] + b0, 0.f); v.y = fmaxf(acc[i][1] + b1, 0.f);
        v.z = fmaxf(acc[i][2] + b2, 0.f); v.w = fmaxf(acc[i][3] + b3, 0.f);
      } else {
        v.x = acc[i][0]; v.y = acc[i][1]; v.z = acc[i][2]; v.w = acc[i][3];
      }
      *(float4*)(out + (size_t)(rb0 + r) * NH + c0) = v;
    }
  }
}

// ---------------- sparse aggregation, 64-ch slice, one wave per dst row ----------------
// Coalesced 256-B single-segment gathers; scalar edge/dinv loads; 16-deep MLP;
// NT store for the output stream (protect the 3.87 MB gather slice in XCD L2).
template<int CH, bool BR>
__global__ __launch_bounds__(256) void agg_h_kernel(const float* __restrict__ src,
                                                    const int* __restrict__ csr,
                                                    const int* __restrict__ rowstart,
                                                    const int* __restrict__ cnt,
                                                    const float* __restrict__ dinv,
                                                    const float* __restrict__ bias,
                                                    float* __restrict__ dst, int half) {
  int b = blockIdx.x & 7;
  int chunk = blockIdx.x >> 3;
  int wave = threadIdx.x >> 6, lane = threadIdx.x & 63;
  int d = chunk * 4 + wave;
  if (d >= N_G) return;
  d = __builtin_amdgcn_readfirstlane(d);
  int c = (CH == 128) ? ((half << 6) + lane) : lane;
  const float* sb = src + (size_t)b * N_G * CH;
  float dv = dinv[d];
  int e0 = rowstart[d];
  int n = cnt[d];
  const int* ce = csr + e0;
  float acc[8];
  acc[0] = dv * sb[(size_t)d * CH + c];
#pragma unroll
  for (int k = 1; k < 8; ++k) acc[k] = 0.f;
  int l = 0;
  for (; l + 16 <= n; l += 16) {
    int ss[16]; float ww[16], vv[16];
#pragma unroll
    for (int k = 0; k < 16; ++k) ss[k] = ce[l + k];
#pragma unroll
    for (int k = 0; k < 16; ++k) ww[k] = dinv[ss[k]];
#pragma unroll
    for (int k = 0; k < 16; ++k) vv[k] = sb[(size_t)ss[k] * CH + c];
#pragma unroll
    for (int k = 0; k < 16; ++k) acc[k & 7] = fmaf(ww[k], vv[k], acc[k & 7]);
  }
  for (; l + 8 <= n; l += 8) {
    int ss[8]; float ww[8], vv[8];
#pragma unroll
    for (int k = 0; k < 8; ++k) ss[k] = ce[l + k];
#pragma unroll
    for (int k = 0; k < 8; ++k) ww[k] = dinv[ss[k]];
#pragma unroll
    for (int k = 0; k < 8; ++k) vv[k] = sb[(size_t)ss[k] * CH + c];
#pragma unroll
    for (int k = 0; k < 8; ++k) acc[k] = fmaf(ww[k], vv[k], acc[k]);
  }
  for (; l < n; ++l) {
    int s = ce[l];
    acc[0] = fmaf(dinv[s], sb[(size_t)s * CH + c], acc[0]);
  }
  float s = ((acc[0] + acc[1]) + (acc[2] + acc[3])) + ((acc[4] + acc[5]) + (acc[6] + acc[7]));
  float r = BR ? fmaxf(fmaf(dv, s, bias[c]), 0.f) : dv * s;
  __builtin_nontemporal_store(r, &dst[((size_t)b * N_G + d) * CH + c]);
}

// ---------------- layer-3 half-agg fused with partial score/fc dots ----------------
__global__ __launch_bounds__(256) void agg_score_h_kernel(const float* __restrict__ hw,
                                                          const int* __restrict__ csr,
                                                          const int* __restrict__ rowstart,
                                                          const int* __restrict__ cnt,
                                                          const float* __restrict__ dinv,
                                                          const float* __restrict__ bias,
                                                          const float* __restrict__ h1,
                                                          const float* __restrict__ h2,
                                                          const float* __restrict__ topk_w,
                                                          const float* __restrict__ fcW,
                                                          float* __restrict__ pd1,
                                                          float* __restrict__ pd2, int half) {
  int b = blockIdx.x & 7;
  int chunk = blockIdx.x >> 3;
  int wave = threadIdx.x >> 6, lane = threadIdx.x & 63;
  int d = chunk * 4 + wave;
  if (d >= N_G) return;
  d = __builtin_amdgcn_readfirstlane(d);
  int c = (half << 6) + lane;
  const float* sb = hw + (size_t)b * N_G * NH;
  float dv = dinv[d];
  int e0 = rowstart[d];
  int n = cnt[d];
  const int* ce = csr + e0;
  float acc[8];
  acc[0] = dv * sb[(size_t)d * NH + c];
#pragma unroll
  for (int k = 1; k < 8; ++k) acc[k] = 0.f;
  int l = 0;
  for (; l + 16 <= n; l += 16) {
    int ss[16]; float ww[16], vv[16];
#pragma unroll
    for (int k = 0; k < 16; ++k) ss[k] = ce[l + k];
#pragma unroll
    for (int k = 0; k < 16; ++k) ww[k] = dinv[ss[k]];
#pragma unroll
    for (int k = 0; k < 16; ++k) vv[k] = sb[(size_t)ss[k] * NH + c];
#pragma unroll
    for (int k = 0; k < 16; ++k) acc[k & 7] = fmaf(ww[k], vv[k], acc[k & 7]);
  }
  for (; l + 8 <= n; l += 8) {
    int ss[8]; float ww[8], vv[8];
#pragma unroll
    for (int k = 0; k < 8; ++k) ss[k] = ce[l + k];
#pragma unroll
    for (int k = 0; k < 8; ++k) ww[k] = dinv[ss[k]];
#pragma unroll
    for (int k = 0; k < 8; ++k) vv[k] = sb[(size_t)ss[k] * NH + c];
#pragma unroll
    for (int k = 0; k < 8; ++k) acc[k] = fmaf(ww[k], vv[k], acc[k]);
  }
  for (; l < n; ++l) {
    int s = ce[l];
    acc[0] = fmaf(dinv[s], sb[(size_t)s * NH + c], acc[0]);
  }
  float s = ((acc[0] + acc[1]) + (acc[2] + acc[3])) + ((acc[4] + acc[5]) + (acc[6] + acc[7]));
  float r = fmaxf(fmaf(dv, s, bias[c]), 0.f);
  // fused partial dots, xc feature order f = c*3 + layer
  size_t rbase = ((size_t)b * N_G + d) * NH + c;
  float u1 = __builtin_nontemporal_load(h1 + rbase);
  float u2 = __builtin_nontemporal_load(h2 + rbase);
  float d1 = u1 * topk_w[c * 3] + u2 * topk_w[c * 3 + 1] + r * topk_w[c * 3 + 2];
  float d2 = u1 * fcW[c * 3]    + u2 * fcW[c * 3 + 1]    + r * fcW[c * 3 + 2];
#pragma unroll
  for (int sh = 32; sh > 0; sh >>= 1) {
    d1 += __shfl_down(d1, sh);
    d2 += __shfl_down(d2, sh);
  }
  if (lane == 0) {
    int gw = b * N_G + d;
    pd1[gw * 2 + half] = d1;
    pd2[gw * 2 + half] = d2;
  }
}

// ---------------- combine halves -> score/key + histogram ----------------
__global__ void combine_kernel(const float* __restrict__ pd1, const float* __restrict__ pd2,
                               const float* __restrict__ scal, float* __restrict__ score,
                               float* __restrict__ d2a, unsigned* __restrict__ keys,
                               int* __restrict__ hist) {
  int b = blockIdx.y;
  int i = blockIdx.x * 256 + threadIdx.x;
  if (i >= N_G) return;
  int gw = b * N_G + i;
  float d1 = pd1[2 * gw] + pd1[2 * gw + 1];
  float d2 = pd2[2 * gw] + pd2[2 * gw + 1];
  float sc = tanhf(d1 * scal[0]);
  score[gw] = sc;
  d2a[gw] = d2;
  unsigned u = __float_as_uint(sc);
  unsigned k32 = (u & 0x80000000u) ? ~u : (u | 0x80000000u);
  keys[gw] = k32;
  atomicAdd(&hist[b * NBIN + (int)(k32 >> 16)], 1);
}

// ---------------- per-batch suffix sums over 65536 bins ----------------
__global__ __launch_bounds__(1024) void suffix_kernel(const int* __restrict__ hist,
                                                      int* __restrict__ suf) {
  __shared__ int buf[1024];
  int b = blockIdx.x;
  const int* hb = hist + b * NBIN;
  int* sb = suf + b * SUFS;
  int t = threadIdx.x;
  int base = t * 64;
  int s = 0;
  for (int k = 0; k < 64; ++k) s += hb[base + k];
  buf[t] = s;
  __syncthreads();
  for (int off = 1; off < 1024; off <<= 1) {
    int v = (t + off < 1024) ? buf[t + off] : 0;
    __syncthreads();
    buf[t] += v;
    __syncthreads();
  }
  int acc = buf[t] - s;
  if (t == 0) sb[NBIN] = 0;
  for (int k = 63; k >= 0; --k) {
    acc += hb[base + k];
    sb[base + k] = acc;
  }
}

// ---------------- bucket scatter (consumes hist via atomicSub) ----------------
__global__ void scatter_kernel(const unsigned* __restrict__ keys, int* __restrict__ hist,
                               const int* __restrict__ suf, int2* __restrict__ bucket) {
  int b = blockIdx.y;
  int i = blockIdx.x * 256 + threadIdx.x;
  if (i >= N_G) return;
  unsigned k = keys[b * N_G + i];
  int bin = (int)(k >> 16);
  int old = atomicSub(&hist[b * NBIN + bin], 1);
  int pos = suf[b * SUFS + bin + 1] + old - 1;
  bucket[b * N_G + pos] = make_int2((int)k, i);
}

// ---------------- exact stable-descending rank + z scatter ----------------
__global__ void rank_z_kernel(const unsigned* __restrict__ keys, const int* __restrict__ suf,
                              const int2* __restrict__ bucket, const float* __restrict__ score,
                              const float* __restrict__ d2a, const float* __restrict__ fcb,
                              float* __restrict__ z) {
  int b = blockIdx.y;
  int i = blockIdx.x * 256 + threadIdx.x;
  if (i >= N_G) return;
  int gw = b * N_G + i;
  unsigned k = keys[gw];
  int bin = (int)(k >> 16);
  int lo = suf[b * SUFS + bin + 1];
  int hi = suf[b * SUFS + bin];
  int r = lo;
  const int2* bk = bucket + b * N_G;
  for (int p = lo; p < hi; ++p) {
    int2 e = bk[p];
    unsigned kj = (unsigned)e.x;
    r += (kj > k || (kj == k && e.y < i)) ? 1 : 0;
  }
  if (r < K_TOP) z[b * K_TOP + r] = fmaf(score[gw], d2a[gw], fcb[0]);
}

// ---------------- lin1 ----------------
__global__ __launch_bounds__(256) void lin1_kernel(const float* __restrict__ z,
                                                   const float* __restrict__ W,
                                                   float* __restrict__ hpre) {
  __shared__ float zb[237];
  int b = blockIdx.y, rs = blockIdx.x;
  int r0 = rs * 237;
  int rn = K_TOP - r0; if (rn > 237) rn = 237;
  for (int q = threadIdx.x; q < rn; q += 256) zb[q] = z[b * K_TOP + r0 + q];
  __syncthreads();
  int c = threadIdx.x;
  float a0 = 0.f, a1 = 0.f;
  for (int r = 0; r < rn; ++r) {
    float zz = zb[r];
    const float* wr = W + (size_t)(r0 + r) * 512;
    a0 = fmaf(zz, wr[c], a0);
    a1 = fmaf(zz, wr[c + 256], a1);
  }
  atomicAdd(&hpre[b * 512 + c], a0);
  atomicAdd(&hpre[b * 512 + c + 256], a1);
}

// ---------------- lin2 + log_softmax ----------------
__global__ __launch_bounds__(128) void lin2_kernel(const float* __restrict__ hpre,
                                                   const float* __restrict__ l1b,
                                                   const float* __restrict__ W2,
                                                   const float* __restrict__ l2b,
                                                   float* __restrict__ out) {
  int b = blockIdx.x, tid = threadIdx.x;
  float a0 = 0.f, a1 = 0.f;
  for (int j = tid; j < 512; j += 128) {
    float t = fmaxf(hpre[b * 512 + j] + l1b[j], 0.f);
    a0 = fmaf(t, W2[j * 2 + 0], a0);
    a1 = fmaf(t, W2[j * 2 + 1], a1);
  }
#pragma unroll
  for (int s = 32; s > 0; s >>= 1) {
    a0 += __shfl_down(a0, s);
    a1 += __shfl_down(a1, s);
  }
  __shared__ float red[2][2];
  if ((tid & 63) == 0) { red[tid >> 6][0] = a0; red[tid >> 6][1] = a1; }
  __syncthreads();
  if (tid == 0) {
    float l0 = red[0][0] + red[1][0] + l2b[0];
    float l1 = red[0][1] + red[1][1] + l2b[1];
    float m = fmaxf(l0, l1);
    float lse = m + logf(expf(l0 - m) + expf(l1 - m));
    out[b * 2 + 0] = l0 - lse;
    out[b * 2 + 1] = l1 - lse;
  }
}

extern "C" void kernel_launch(void* const* d_in, const int* in_sizes, int n_in,
                              void* d_out, int out_size, void* d_ws, size_t ws_size,
                              hipStream_t stream) {
  const float* x   = (const float*)d_in[0];
  const int*   ei  = (const int*)d_in[2];
  const float* W1  = (const float*)d_in[3];
  const float* b1  = (const float*)d_in[4];
  const float* W2  = (const float*)d_in[5];
  const float* b2  = (const float*)d_in[6];
  const float* W3  = (const float*)d_in[7];
  const float* b3  = (const float*)d_in[8];
  const float* tkw = (const float*)d_in[9];
  const float* fcW = (const float*)d_in[10];
  const float* fcb = (const float*)d_in[11];
  const float* l1W = (const float*)d_in[12];
  const float* l1b = (const float*)d_in[13];
  const float* l2W = (const float*)d_in[14];
  const float* l2b = (const float*)d_in[15];
  float* out = (float*)d_out;

  char* ws = (char*)d_ws;
  size_t off = 0;
  auto alloc = [&](size_t bytes) {
    char* p = ws + off;
    off += (bytes + 255) & ~(size_t)255;
    return p;
  };
  // zero-init region (contiguous): cnt, fillc, gctr, hpre, hist
  int*   cnt   = (int*)alloc(15136 * 4);
  int*   fillc = (int*)alloc(15136 * 4);
  int*   gctr  = (int*)alloc(256);
  float* hpre  = (float*)alloc(4096 * 4);
  int*   hist  = (int*)alloc((size_t)BSZ * NBIN * 4);
  // --- end zero region ---
  int*   rowstart = (int*)alloc(15136 * 4);
  float* dinv  = (float*)alloc(15136 * 4);
  float* scal  = (float*)alloc(64);
  float* z     = (float*)alloc((size_t)BSZ * K_TOP * 4);
  float* score = (float*)alloc(121088 * 4);
  float* d2a   = (float*)alloc(121088 * 4);
  unsigned* keys = (unsigned*)alloc(121088 * 4);
  int*   suf   = (int*)alloc((size_t)BSZ * SUFS * 4);
  int2*  bucket = (int2*)alloc(121088 * 8);
  float* pd1   = (float*)alloc(121088 * 2 * 4);
  float* pd2   = (float*)alloc(121088 * 2 * 4);
  int*   csr   = (int*)alloc((size_t)E_N * 4);
  float* ax = (float*)alloc((size_t)BSZ * N_G * 64 * 4);
  float* hw = (float*)alloc((size_t)BSZ * N_G * NH * 4);
  float* h1 = (float*)alloc((size_t)BSZ * N_G * NH * 4);
  float* h2 = (float*)alloc((size_t)BSZ * N_G * NH * 4);
  (void)ws_size; (void)in_sizes; (void)n_in; (void)out_size;

  int zero_n = (int)(((char*)rowstart - (char*)cnt) / 4);
  zero_kernel<<<(zero_n + 1023) / 1024, 1024, 0, stream>>>(cnt, zero_n);
  count_kernel<<<(E_N + 255) / 256, 256, 0, stream>>>(ei, cnt);
  scan_kernel<<<(N_G + 1023) / 1024, 1024, 0, stream>>>(cnt, rowstart, dinv, gctr, tkw, scal);
  fill_kernel<<<(E_N + 255) / 256, 256, 0, stream>>>(ei, rowstart, fillc, csr);

  dim3 mmg(8 * 237);  // batch-pinned: b = blk&7
  int aggblocks = 8 * ((N_G + 3) / 4);

  // layer 1: agg(x) @ W1 (commutation) — one 64-ch agg dispatch + fused-bias mm
  agg_h_kernel<64, false><<<aggblocks, 256, 0, stream>>>(x, csr, rowstart, cnt, dinv, nullptr, ax, 0);
  mm_kernel<64, true><<<mmg, 256, 0, stream>>>(ax, W1, b1, h1);
  // layer 2
  mm_kernel<128, false><<<mmg, 256, 0, stream>>>(h1, W2, nullptr, hw);
  agg_h_kernel<128, true><<<aggblocks, 256, 0, stream>>>(hw, csr, rowstart, cnt, dinv, b2, h2, 0);
  agg_h_kernel<128, true><<<aggblocks, 256, 0, stream>>>(hw, csr, rowstart, cnt, dinv, b2, h2, 1);
  // layer 3 fused with score partials
  mm_kernel<128, false><<<mmg, 256, 0, stream>>>(h2, W3, nullptr, hw);
  agg_score_h_kernel<<<aggblocks, 256, 0, stream>>>(hw, csr, rowstart, cnt, dinv, b3,
                                                    h1, h2, tkw, fcW, pd1, pd2, 0);
  agg_score_h_kernel<<<aggblocks, 256, 0, stream>>>(hw, csr, rowstart, cnt, dinv, b3,
                                                    h1, h2, tkw, fcW, pd1, pd2, 1);

  dim3 ng((N_G + 255) / 256, BSZ);
  combine_kernel<<<ng, 256, 0, stream>>>(pd1, pd2, scal, score, d2a, keys, hist);
  suffix_kernel<<<BSZ, 1024, 0, stream>>>(hist, suf);
  scatter_kernel<<<ng, 256, 0, stream>>>(keys, hist, suf, bucket);
  rank_z_kernel<<<ng, 256, 0, stream>>>(keys, suf, bucket, score, d2a, fcb, z);

  dim3 l1g(32, BSZ);
  lin1_kernel<<<l1g, 256, 0, stream>>>(z, l1W, hpre);
  lin2_kernel<<<BSZ, 128, 0, stream>>>(hpre, l1b, l2W, l2b, out);
}

// Round 10
// 694.345 us; speedup vs baseline: 1.5348x; 1.0440x over previous
//
#include <hip/hip_runtime.h>

#define N_G   15135
#define E_N   242160
#define BSZ   8
#define K_TOP 7568
#define NH    128
#define NBIN  65536
#define SUFS  65600

typedef float f4v __attribute__((ext_vector_type(4)));

// ---------------- utility ----------------
__global__ void zero_kernel(int* __restrict__ p, int n) {
  int i = blockIdx.x * 1024 + threadIdx.x;
  if (i < n) p[i] = 0;
}

__global__ void count_kernel(const int* __restrict__ ei, int* __restrict__ cnt) {
  int e = blockIdx.x * 256 + threadIdx.x;
  if (e < E_N) atomicAdd(&cnt[ei[E_N + e]], 1);
}

__global__ __launch_bounds__(1024) void scan_kernel(const int* __restrict__ cnt,
                                                    int* __restrict__ rowstart,
                                                    float* __restrict__ dinv,
                                                    int* __restrict__ gctr,
                                                    const float* __restrict__ topk_w,
                                                    float* __restrict__ scal) {
  __shared__ int buf[1024];
  __shared__ int base;
  int tid = threadIdx.x;
  int i = blockIdx.x * 1024 + tid;
  int v = (i < N_G) ? cnt[i] : 0;
  if (i < N_G) dinv[i] = 1.0f / sqrtf((float)(v + 1));
  buf[tid] = v;
  __syncthreads();
  for (int s = 1; s < 1024; s <<= 1) {
    int t = (tid >= s) ? buf[tid - s] : 0;
    __syncthreads();
    buf[tid] += t;
    __syncthreads();
  }
  if (tid == 1023) base = atomicAdd(gctr, buf[1023]);
  __syncthreads();
  if (i < N_G) rowstart[i] = base + buf[tid] - v;
  if (blockIdx.x == 0) {
    __shared__ float fbuf[512];
    if (tid < 512) {
      float w = (tid < 384) ? topk_w[tid] : 0.f;
      fbuf[tid] = w * w;
    }
    __syncthreads();
    for (int s = 256; s > 0; s >>= 1) {
      if (tid < s) fbuf[tid] += fbuf[tid + s];
      __syncthreads();
    }
    if (tid == 0) scal[0] = 1.0f / sqrtf(fbuf[0]);
  }
}

// csr entry packs (src, dinv[src]) -> edge weights arrive with the contiguous
// scalar edge-block load; no scattered dinv lookups on the critical path.
__global__ void fill_kernel(const int* __restrict__ ei, const int* __restrict__ rowstart,
                            const float* __restrict__ dinv, int* __restrict__ fillc,
                            int2* __restrict__ csr) {
  int e = blockIdx.x * 256 + threadIdx.x;
  if (e < E_N) {
    int s = ei[e], d = ei[E_N + e];
    int pos = rowstart[d] + atomicAdd(&fillc[d], 1);
    csr[pos] = make_int2(s, __float_as_int(dinv[s]));
  }
}

// ---------------- dense matmul, batch-pinned blocks ----------------
template<int CIN, bool BR>
__global__ __launch_bounds__(256, 6) void mm_kernel(const float* __restrict__ A,
                                                    const float* __restrict__ W,
                                                    const float* __restrict__ bias,
                                                    float* __restrict__ out) {
  __shared__ float Bst[32][132];
  __shared__ float Ast2[32][68];
  int tid = threadIdx.x;
  int b = blockIdx.x & 7;
  int ib = blockIdx.x >> 3;
  int rb0 = b * N_G + ib * 64;
  int rmax = N_G - ib * 64;
  int c0 = (tid & 31) * 4;
  int r0 = (tid >> 5) * 8;
  float acc[8][4];
#pragma unroll
  for (int i = 0; i < 8; i++)
#pragma unroll
    for (int j = 0; j < 4; j++) acc[i][j] = 0.f;

  for (int k0 = 0; k0 < CIN; k0 += 32) {
    {
      int koff = (tid & 7) * 4;
      int row = tid >> 3;
#pragma unroll
      for (int p = 0; p < 2; ++p) {
        int r = row + p * 32;
        f4v v = {0.f, 0.f, 0.f, 0.f};
        if (r < rmax) v = __builtin_nontemporal_load((const f4v*)(A + (size_t)(rb0 + r) * CIN + k0 + koff));
        Ast2[koff + 0][r] = v.x; Ast2[koff + 1][r] = v.y;
        Ast2[koff + 2][r] = v.z; Ast2[koff + 3][r] = v.w;
      }
    }
    {
      int cc = (tid & 31) * 4;
      int kr = tid >> 5;
#pragma unroll
      for (int p = 0; p < 4; ++p) {
        int k = kr + p * 8;
        *(float4*)&Bst[k][cc] = *(const float4*)(W + (size_t)(k0 + k) * NH + cc);
      }
    }
    __syncthreads();
#pragma unroll 4
    for (int kk = 0; kk < 32; ++kk) {
      float a[8], bb[4];
      *(float4*)&a[0] = *(const float4*)&Ast2[kk][r0];
      *(float4*)&a[4] = *(const float4*)&Ast2[kk][r0 + 4];
      *(float4*)&bb[0] = *(const float4*)&Bst[kk][c0];
#pragma unroll
      for (int i = 0; i < 8; i++)
#pragma unroll
        for (int j = 0; j < 4; j++)
          acc[i][j] = fmaf(a[i], bb[j], acc[i][j]);
    }
    __syncthreads();
  }
  float b0 = 0.f, b1 = 0.f, b2 = 0.f, b3 = 0.f;
  if (BR) { b0 = bias[c0]; b1 = bias[c0+1]; b2 = bias[c0+2]; b3 = bias[c0+3]; }
#pragma unroll
  for (int i = 0; i < 8; i++) {
    int r = r0 + i;
    if (r < rmax) {
      float4 v;
      if (BR) {
        v.x = fmaxf(acc[i][0] + b0, 0.f); v.y = fmaxf(acc[i][1] + b1, 0.f);
        v.z = fmaxf(acc[i][2] + b2, 0.f); v.w = fmaxf(acc[i][3] + b3, 0.f);
      } else {
        v.x = acc[i][0]; v.y = acc[i][1]; v.z = acc[i][2]; v.w = acc[i][3];
      }
      *(float4*)(out + (size_t)(rb0 + r) * NH + c0) = v;
    }
  }
}

// ---------------- sparse aggregation, 64-ch slice, one wave per dst row ----------------
// int2 csr: one contiguous scalar edge-block load delivers src+weight for 8 edges;
// gathers are the only vector-memory ops. NT store protects the L2 gather slice.
template<int CH, bool BR>
__global__ __launch_bounds__(256) void agg_h_kernel(const float* __restrict__ src,
                                                    const int2* __restrict__ csr,
                                                    const int* __restrict__ rowstart,
                                                    const int* __restrict__ cnt,
                                                    const float* __restrict__ dinv,
                                                    const float* __restrict__ bias,
                                                    float* __restrict__ dst, int half) {
  int b = blockIdx.x & 7;
  int chunk = blockIdx.x >> 3;
  int wave = threadIdx.x >> 6, lane = threadIdx.x & 63;
  int d = chunk * 4 + wave;
  if (d >= N_G) return;
  d = __builtin_amdgcn_readfirstlane(d);
  int c = (CH == 128) ? ((half << 6) + lane) : lane;
  const float* sb = src + (size_t)b * N_G * CH;
  float dv = dinv[d];
  int e0 = rowstart[d];
  int n = cnt[d];
  const int2* ce = csr + e0;
  float acc[8];
  acc[0] = dv * sb[(size_t)d * CH + c];
#pragma unroll
  for (int k = 1; k < 8; ++k) acc[k] = 0.f;
  int l = 0;
  for (; l + 8 <= n; l += 8) {
    int2 p0 = ce[l+0], p1 = ce[l+1], p2 = ce[l+2], p3 = ce[l+3];
    int2 p4 = ce[l+4], p5 = ce[l+5], p6 = ce[l+6], p7 = ce[l+7];
    float v0 = sb[(size_t)p0.x * CH + c];
    float v1 = sb[(size_t)p1.x * CH + c];
    float v2 = sb[(size_t)p2.x * CH + c];
    float v3 = sb[(size_t)p3.x * CH + c];
    float v4 = sb[(size_t)p4.x * CH + c];
    float v5 = sb[(size_t)p5.x * CH + c];
    float v6 = sb[(size_t)p6.x * CH + c];
    float v7 = sb[(size_t)p7.x * CH + c];
    acc[0] = fmaf(__int_as_float(p0.y), v0, acc[0]);
    acc[1] = fmaf(__int_as_float(p1.y), v1, acc[1]);
    acc[2] = fmaf(__int_as_float(p2.y), v2, acc[2]);
    acc[3] = fmaf(__int_as_float(p3.y), v3, acc[3]);
    acc[4] = fmaf(__int_as_float(p4.y), v4, acc[4]);
    acc[5] = fmaf(__int_as_float(p5.y), v5, acc[5]);
    acc[6] = fmaf(__int_as_float(p6.y), v6, acc[6]);
    acc[7] = fmaf(__int_as_float(p7.y), v7, acc[7]);
  }
  for (; l < n; ++l) {
    int2 p = ce[l];
    acc[0] = fmaf(__int_as_float(p.y), sb[(size_t)p.x * CH + c], acc[0]);
  }
  float s = ((acc[0] + acc[1]) + (acc[2] + acc[3])) + ((acc[4] + acc[5]) + (acc[6] + acc[7]));
  float r = BR ? fmaxf(fmaf(dv, s, bias[c]), 0.f) : dv * s;
  __builtin_nontemporal_store(r, &dst[((size_t)b * N_G + d) * CH + c]);
}

// ---------------- layer-3 half-agg fused with partial score/fc dots ----------------
__global__ __launch_bounds__(256) void agg_score_h_kernel(const float* __restrict__ hw,
                                                          const int2* __restrict__ csr,
                                                          const int* __restrict__ rowstart,
                                                          const int* __restrict__ cnt,
                                                          const float* __restrict__ dinv,
                                                          const float* __restrict__ bias,
                                                          const float* __restrict__ h1,
                                                          const float* __restrict__ h2,
                                                          const float* __restrict__ topk_w,
                                                          const float* __restrict__ fcW,
                                                          float* __restrict__ pd1,
                                                          float* __restrict__ pd2, int half) {
  int b = blockIdx.x & 7;
  int chunk = blockIdx.x >> 3;
  int wave = threadIdx.x >> 6, lane = threadIdx.x & 63;
  int d = chunk * 4 + wave;
  if (d >= N_G) return;
  d = __builtin_amdgcn_readfirstlane(d);
  int c = (half << 6) + lane;
  const float* sb = hw + (size_t)b * N_G * NH;
  float dv = dinv[d];
  int e0 = rowstart[d];
  int n = cnt[d];
  const int2* ce = csr + e0;
  float acc[8];
  acc[0] = dv * sb[(size_t)d * NH + c];
#pragma unroll
  for (int k = 1; k < 8; ++k) acc[k] = 0.f;
  int l = 0;
  for (; l + 8 <= n; l += 8) {
    int2 p0 = ce[l+0], p1 = ce[l+1], p2 = ce[l+2], p3 = ce[l+3];
    int2 p4 = ce[l+4], p5 = ce[l+5], p6 = ce[l+6], p7 = ce[l+7];
    float v0 = sb[(size_t)p0.x * NH + c];
    float v1 = sb[(size_t)p1.x * NH + c];
    float v2 = sb[(size_t)p2.x * NH + c];
    float v3 = sb[(size_t)p3.x * NH + c];
    float v4 = sb[(size_t)p4.x * NH + c];
    float v5 = sb[(size_t)p5.x * NH + c];
    float v6 = sb[(size_t)p6.x * NH + c];
    float v7 = sb[(size_t)p7.x * NH + c];
    acc[0] = fmaf(__int_as_float(p0.y), v0, acc[0]);
    acc[1] = fmaf(__int_as_float(p1.y), v1, acc[1]);
    acc[2] = fmaf(__int_as_float(p2.y), v2, acc[2]);
    acc[3] = fmaf(__int_as_float(p3.y), v3, acc[3]);
    acc[4] = fmaf(__int_as_float(p4.y), v4, acc[4]);
    acc[5] = fmaf(__int_as_float(p5.y), v5, acc[5]);
    acc[6] = fmaf(__int_as_float(p6.y), v6, acc[6]);
    acc[7] = fmaf(__int_as_float(p7.y), v7, acc[7]);
  }
  for (; l < n; ++l) {
    int2 p = ce[l];
    acc[0] = fmaf(__int_as_float(p.y), sb[(size_t)p.x * NH + c], acc[0]);
  }
  float s = ((acc[0] + acc[1]) + (acc[2] + acc[3])) + ((acc[4] + acc[5]) + (acc[6] + acc[7]));
  float r = fmaxf(fmaf(dv, s, bias[c]), 0.f);
  // fused partial dots, xc feature order f = c*3 + layer
  size_t rbase = ((size_t)b * N_G + d) * NH + c;
  float u1 = __builtin_nontemporal_load(h1 + rbase);
  float u2 = __builtin_nontemporal_load(h2 + rbase);
  float d1 = u1 * topk_w[c * 3] + u2 * topk_w[c * 3 + 1] + r * topk_w[c * 3 + 2];
  float d2 = u1 * fcW[c * 3]    + u2 * fcW[c * 3 + 1]    + r * fcW[c * 3 + 2];
#pragma unroll
  for (int sh = 32; sh > 0; sh >>= 1) {
    d1 += __shfl_down(d1, sh);
    d2 += __shfl_down(d2, sh);
  }
  if (lane == 0) {
    int gw = b * N_G + d;
    pd1[gw * 2 + half] = d1;
    pd2[gw * 2 + half] = d2;
  }
}

// ---------------- combine halves -> score/key + histogram ----------------
__global__ void combine_kernel(const float* __restrict__ pd1, const float* __restrict__ pd2,
                               const float* __restrict__ scal, float* __restrict__ score,
                               float* __restrict__ d2a, unsigned* __restrict__ keys,
                               int* __restrict__ hist) {
  int b = blockIdx.y;
  int i = blockIdx.x * 256 + threadIdx.x;
  if (i >= N_G) return;
  int gw = b * N_G + i;
  float d1 = pd1[2 * gw] + pd1[2 * gw + 1];
  float d2 = pd2[2 * gw] + pd2[2 * gw + 1];
  float sc = tanhf(d1 * scal[0]);
  score[gw] = sc;
  d2a[gw] = d2;
  unsigned u = __float_as_uint(sc);
  unsigned k32 = (u & 0x80000000u) ? ~u : (u | 0x80000000u);
  keys[gw] = k32;
  atomicAdd(&hist[b * NBIN + (int)(k32 >> 16)], 1);
}

// ---------------- per-batch suffix sums over 65536 bins ----------------
__global__ __launch_bounds__(1024) void suffix_kernel(const int* __restrict__ hist,
                                                      int* __restrict__ suf) {
  __shared__ int buf[1024];
  int b = blockIdx.x;
  const int* hb = hist + b * NBIN;
  int* sb = suf + b * SUFS;
  int t = threadIdx.x;
  int base = t * 64;
  int s = 0;
  for (int k = 0; k < 64; ++k) s += hb[base + k];
  buf[t] = s;
  __syncthreads();
  for (int off = 1; off < 1024; off <<= 1) {
    int v = (t + off < 1024) ? buf[t + off] : 0;
    __syncthreads();
    buf[t] += v;
    __syncthreads();
  }
  int acc = buf[t] - s;
  if (t == 0) sb[NBIN] = 0;
  for (int k = 63; k >= 0; --k) {
    acc += hb[base + k];
    sb[base + k] = acc;
  }
}

// ---------------- bucket scatter (consumes hist via atomicSub) ----------------
__global__ void scatter_kernel(const unsigned* __restrict__ keys, int* __restrict__ hist,
                               const int* __restrict__ suf, int2* __restrict__ bucket) {
  int b = blockIdx.y;
  int i = blockIdx.x * 256 + threadIdx.x;
  if (i >= N_G) return;
  unsigned k = keys[b * N_G + i];
  int bin = (int)(k >> 16);
  int old = atomicSub(&hist[b * NBIN + bin], 1);
  int pos = suf[b * SUFS + bin + 1] + old - 1;
  bucket[b * N_G + pos] = make_int2((int)k, i);
}

// ---------------- exact stable-descending rank + z scatter ----------------
__global__ void rank_z_kernel(const unsigned* __restrict__ keys, const int* __restrict__ suf,
                              const int2* __restrict__ bucket, const float* __restrict__ score,
                              const float* __restrict__ d2a, const float* __restrict__ fcb,
                              float* __restrict__ z) {
  int b = blockIdx.y;
  int i = blockIdx.x * 256 + threadIdx.x;
  if (i >= N_G) return;
  int gw = b * N_G + i;
  unsigned k = keys[gw];
  int bin = (int)(k >> 16);
  int lo = suf[b * SUFS + bin + 1];
  int hi = suf[b * SUFS + bin];
  int r = lo;
  const int2* bk = bucket + b * N_G;
  for (int p = lo; p < hi; ++p) {
    int2 e = bk[p];
    unsigned kj = (unsigned)e.x;
    r += (kj > k || (kj == k && e.y < i)) ? 1 : 0;
  }
  if (r < K_TOP) z[b * K_TOP + r] = fmaf(score[gw], d2a[gw], fcb[0]);
}

// ---------------- lin1 ----------------
__global__ __launch_bounds__(256) void lin1_kernel(const float* __restrict__ z,
                                                   const float* __restrict__ W,
                                                   float* __restrict__ hpre) {
  __shared__ float zb[237];
  int b = blockIdx.y, rs = blockIdx.x;
  int r0 = rs * 237;
  int rn = K_TOP - r0; if (rn > 237) rn = 237;
  for (int q = threadIdx.x; q < rn; q += 256) zb[q] = z[b * K_TOP + r0 + q];
  __syncthreads();
  int c = threadIdx.x;
  float a0 = 0.f, a1 = 0.f;
  for (int r = 0; r < rn; ++r) {
    float zz = zb[r];
    const float* wr = W + (size_t)(r0 + r) * 512;
    a0 = fmaf(zz, wr[c], a0);
    a1 = fmaf(zz, wr[c + 256], a1);
  }
  atomicAdd(&hpre[b * 512 + c], a0);
  atomicAdd(&hpre[b * 512 + c + 256], a1);
}

// ---------------- lin2 + log_softmax ----------------
__global__ __launch_bounds__(128) void lin2_kernel(const float* __restrict__ hpre,
                                                   const float* __restrict__ l1b,
                                                   const float* __restrict__ W2,
                                                   const float* __restrict__ l2b,
                                                   float* __restrict__ out) {
  int b = blockIdx.x, tid = threadIdx.x;
  float a0 = 0.f, a1 = 0.f;
  for (int j = tid; j < 512; j += 128) {
    float t = fmaxf(hpre[b * 512 + j] + l1b[j], 0.f);
    a0 = fmaf(t, W2[j * 2 + 0], a0);
    a1 = fmaf(t, W2[j * 2 + 1], a1);
  }
#pragma unroll
  for (int s = 32; s > 0; s >>= 1) {
    a0 += __shfl_down(a0, s);
    a1 += __shfl_down(a1, s);
  }
  __shared__ float red[2][2];
  if ((tid & 63) == 0) { red[tid >> 6][0] = a0; red[tid >> 6][1] = a1; }
  __syncthreads();
  if (tid == 0) {
    float l0 = red[0][0] + red[1][0] + l2b[0];
    float l1 = red[0][1] + red[1][1] + l2b[1];
    float m = fmaxf(l0, l1);
    float lse = m + logf(expf(l0 - m) + expf(l1 - m));
    out[b * 2 + 0] = l0 - lse;
    out[b * 2 + 1] = l1 - lse;
  }
}

extern "C" void kernel_launch(void* const* d_in, const int* in_sizes, int n_in,
                              void* d_out, int out_size, void* d_ws, size_t ws_size,
                              hipStream_t stream) {
  const float* x   = (const float*)d_in[0];
  const int*   ei  = (const int*)d_in[2];
  const float* W1  = (const float*)d_in[3];
  const float* b1  = (const float*)d_in[4];
  const float* W2  = (const float*)d_in[5];
  const float* b2  = (const float*)d_in[6];
  const float* W3  = (const float*)d_in[7];
  const float* b3  = (const float*)d_in[8];
  const float* tkw = (const float*)d_in[9];
  const float* fcW = (const float*)d_in[10];
  const float* fcb = (const float*)d_in[11];
  const float* l1W = (const float*)d_in[12];
  const float* l1b = (const float*)d_in[13];
  const float* l2W = (const float*)d_in[14];
  const float* l2b = (const float*)d_in[15];
  float* out = (float*)d_out;

  char* ws = (char*)d_ws;
  size_t off = 0;
  auto alloc = [&](size_t bytes) {
    char* p = ws + off;
    off += (bytes + 255) & ~(size_t)255;
    return p;
  };
  // zero-init region (contiguous): cnt, fillc, gctr, hpre, hist
  int*   cnt   = (int*)alloc(15136 * 4);
  int*   fillc = (int*)alloc(15136 * 4);
  int*   gctr  = (int*)alloc(256);
  float* hpre  = (float*)alloc(4096 * 4);
  int*   hist  = (int*)alloc((size_t)BSZ * NBIN * 4);
  // --- end zero region ---
  int*   rowstart = (int*)alloc(15136 * 4);
  float* dinv  = (float*)alloc(15136 * 4);
  float* scal  = (float*)alloc(64);
  float* z     = (float*)alloc((size_t)BSZ * K_TOP * 4);
  float* score = (float*)alloc(121088 * 4);
  float* d2a   = (float*)alloc(121088 * 4);
  unsigned* keys = (unsigned*)alloc(121088 * 4);
  int*   suf   = (int*)alloc((size_t)BSZ * SUFS * 4);
  int2*  bucket = (int2*)alloc(121088 * 8);
  float* pd1   = (float*)alloc(121088 * 2 * 4);
  float* pd2   = (float*)alloc(121088 * 2 * 4);
  int2*  csr   = (int2*)alloc((size_t)E_N * 8);
  float* ax = (float*)alloc((size_t)BSZ * N_G * 64 * 4);
  float* hw = (float*)alloc((size_t)BSZ * N_G * NH * 4);
  float* h1 = (float*)alloc((size_t)BSZ * N_G * NH * 4);
  float* h2 = (float*)alloc((size_t)BSZ * N_G * NH * 4);
  (void)ws_size; (void)in_sizes; (void)n_in; (void)out_size;

  int zero_n = (int)(((char*)rowstart - (char*)cnt) / 4);
  zero_kernel<<<(zero_n + 1023) / 1024, 1024, 0, stream>>>(cnt, zero_n);
  count_kernel<<<(E_N + 255) / 256, 256, 0, stream>>>(ei, cnt);
  scan_kernel<<<(N_G + 1023) / 1024, 1024, 0, stream>>>(cnt, rowstart, dinv, gctr, tkw, scal);
  fill_kernel<<<(E_N + 255) / 256, 256, 0, stream>>>(ei, rowstart, dinv, fillc, csr);

  dim3 mmg(8 * 237);  // batch-pinned: b = blk&7
  int aggblocks = 8 * ((N_G + 3) / 4);

  // layer 1: agg(x) @ W1 (commutation) — one 64-ch agg dispatch + fused-bias mm
  agg_h_kernel<64, false><<<aggblocks, 256, 0, stream>>>(x, csr, rowstart, cnt, dinv, nullptr, ax, 0);
  mm_kernel<64, true><<<mmg, 256, 0, stream>>>(ax, W1, b1, h1);
  // layer 2
  mm_kernel<128, false><<<mmg, 256, 0, stream>>>(h1, W2, nullptr, hw);
  agg_h_kernel<128, true><<<aggblocks, 256, 0, stream>>>(hw, csr, rowstart, cnt, dinv, b2, h2, 0);
  agg_h_kernel<128, true><<<aggblocks, 256, 0, stream>>>(hw, csr, rowstart, cnt, dinv, b2, h2, 1);
  // layer 3 fused with score partials
  mm_kernel<128, false><<<mmg, 256, 0, stream>>>(h2, W3, nullptr, hw);
  agg_score_h_kernel<<<aggblocks, 256, 0, stream>>>(hw, csr, rowstart, cnt, dinv, b3,
                                                    h1, h2, tkw, fcW, pd1, pd2, 0);
  agg_score_h_kernel<<<aggblocks, 256, 0, stream>>>(hw, csr, rowstart, cnt, dinv, b3,
                                                    h1, h2, tkw, fcW, pd1, pd2, 1);

  dim3 ng((N_G + 255) / 256, BSZ);
  combine_kernel<<<ng, 256, 0, stream>>>(pd1, pd2, scal, score, d2a, keys, hist);
  suffix_kernel<<<BSZ, 1024, 0, stream>>>(hist, suf);
  scatter_kernel<<<ng, 256, 0, stream>>>(keys, hist, suf, bucket);
  rank_z_kernel<<<ng, 256, 0, stream>>>(keys, suf, bucket, score, d2a, fcb, z);

  dim3 l1g(32, BSZ);
  lin1_kernel<<<l1g, 256, 0, stream>>>(z, l1W, hpre);
  lin2_kernel<<<BSZ, 128, 0, stream>>>(hpre, l1b, l2W, l2b, out);
}

// Round 11
// 663.394 us; speedup vs baseline: 1.6064x; 1.0467x over previous
//
#include <hip/hip_runtime.h>

#define N_G   15135
#define E_N   242160
#define BSZ   8
#define K_TOP 7568
#define NH    128
#define NBIN  65536
#define SUFS  65600

typedef float f4v __attribute__((ext_vector_type(4)));

// ---------------- utility ----------------
__global__ void zero_kernel(int* __restrict__ p, int n) {
  int i = blockIdx.x * 1024 + threadIdx.x;
  if (i < n) p[i] = 0;
}

__global__ void count_kernel(const int* __restrict__ ei, int* __restrict__ cnt) {
  int e = blockIdx.x * 256 + threadIdx.x;
  if (e < E_N) atomicAdd(&cnt[ei[E_N + e]], 1);
}

// local scan + atomic ticket; emits dinv, packed row descriptor (rowstart,cnt,dinv), scal.
__global__ __launch_bounds__(1024) void scan_kernel(const int* __restrict__ cnt,
                                                    int* __restrict__ rowstart,
                                                    float* __restrict__ dinv,
                                                    int4* __restrict__ rowdesc,
                                                    int* __restrict__ gctr,
                                                    const float* __restrict__ topk_w,
                                                    float* __restrict__ scal) {
  __shared__ int buf[1024];
  __shared__ int base;
  int tid = threadIdx.x;
  int i = blockIdx.x * 1024 + tid;
  int v = (i < N_G) ? cnt[i] : 0;
  float di = 1.0f / sqrtf((float)(v + 1));
  if (i < N_G) dinv[i] = di;
  buf[tid] = v;
  __syncthreads();
  for (int s = 1; s < 1024; s <<= 1) {
    int t = (tid >= s) ? buf[tid - s] : 0;
    __syncthreads();
    buf[tid] += t;
    __syncthreads();
  }
  if (tid == 1023) base = atomicAdd(gctr, buf[1023]);
  __syncthreads();
  if (i < N_G) {
    int rs = base + buf[tid] - v;
    rowstart[i] = rs;
    rowdesc[i] = make_int4(rs, v, __float_as_int(di), 0);
  }
  if (blockIdx.x == 0) {
    __shared__ float fbuf[512];
    if (tid < 512) {
      float w = (tid < 384) ? topk_w[tid] : 0.f;
      fbuf[tid] = w * w;
    }
    __syncthreads();
    for (int s = 256; s > 0; s >>= 1) {
      if (tid < s) fbuf[tid] += fbuf[tid + s];
      __syncthreads();
    }
    if (tid == 0) scal[0] = 1.0f / sqrtf(fbuf[0]);
  }
}

// csr packs (src, dinv[src]).
__global__ void fill_kernel(const int* __restrict__ ei, const int* __restrict__ rowstart,
                            const float* __restrict__ dinv, int* __restrict__ fillc,
                            int2* __restrict__ csr) {
  int e = blockIdx.x * 256 + threadIdx.x;
  if (e < E_N) {
    int s = ei[e], d = ei[E_N + e];
    int pos = rowstart[d] + atomicAdd(&fillc[d], 1);
    csr[pos] = make_int2(s, __float_as_int(dinv[s]));
  }
}

// ---------------- dense matmul, batch-pinned blocks ----------------
template<int CIN, bool BR>
__global__ __launch_bounds__(256, 6) void mm_kernel(const float* __restrict__ A,
                                                    const float* __restrict__ W,
                                                    const float* __restrict__ bias,
                                                    float* __restrict__ out) {
  __shared__ float Bst[32][132];
  __shared__ float Ast2[32][68];
  int tid = threadIdx.x;
  int b = blockIdx.x & 7;
  int ib = blockIdx.x >> 3;
  int rb0 = b * N_G + ib * 64;
  int rmax = N_G - ib * 64;
  int c0 = (tid & 31) * 4;
  int r0 = (tid >> 5) * 8;
  float acc[8][4];
#pragma unroll
  for (int i = 0; i < 8; i++)
#pragma unroll
    for (int j = 0; j < 4; j++) acc[i][j] = 0.f;

  for (int k0 = 0; k0 < CIN; k0 += 32) {
    {
      int koff = (tid & 7) * 4;
      int row = tid >> 3;
#pragma unroll
      for (int p = 0; p < 2; ++p) {
        int r = row + p * 32;
        f4v v = {0.f, 0.f, 0.f, 0.f};
        if (r < rmax) v = __builtin_nontemporal_load((const f4v*)(A + (size_t)(rb0 + r) * CIN + k0 + koff));
        Ast2[koff + 0][r] = v.x; Ast2[koff + 1][r] = v.y;
        Ast2[koff + 2][r] = v.z; Ast2[koff + 3][r] = v.w;
      }
    }
    {
      int cc = (tid & 31) * 4;
      int kr = tid >> 5;
#pragma unroll
      for (int p = 0; p < 4; ++p) {
        int k = kr + p * 8;
        *(float4*)&Bst[k][cc] = *(const float4*)(W + (size_t)(k0 + k) * NH + cc);
      }
    }
    __syncthreads();
#pragma unroll 4
    for (int kk = 0; kk < 32; ++kk) {
      float a[8], bb[4];
      *(float4*)&a[0] = *(const float4*)&Ast2[kk][r0];
      *(float4*)&a[4] = *(const float4*)&Ast2[kk][r0 + 4];
      *(float4*)&bb[0] = *(const float4*)&Bst[kk][c0];
#pragma unroll
      for (int i = 0; i < 8; i++)
#pragma unroll
        for (int j = 0; j < 4; j++)
          acc[i][j] = fmaf(a[i], bb[j], acc[i][j]);
    }
    __syncthreads();
  }
  float b0 = 0.f, b1 = 0.f, b2 = 0.f, b3 = 0.f;
  if (BR) { b0 = bias[c0]; b1 = bias[c0+1]; b2 = bias[c0+2]; b3 = bias[c0+3]; }
#pragma unroll
  for (int i = 0; i < 8; i++) {
    int r = r0 + i;
    if (r < rmax) {
      float4 v;
      if (BR) {
        v.x = fmaxf(acc[i][0] + b0, 0.f); v.y = fmaxf(acc[i][1] + b1, 0.f);
        v.z = fmaxf(acc[i][2] + b2, 0.f); v.w = fmaxf(acc[i][3] + b3, 0.f);
      } else {
        v.x = acc[i][0]; v.y = acc[i][1]; v.z = acc[i][2]; v.w = acc[i][3];
      }
      *(float4*)(out + (size_t)(rb0 + r) * NH + c0) = v;
    }
  }
}

// ---------------- sparse aggregation, 64-ch slice, software-pipelined gathers -----------
// Double-buffered 8-edge blocks: gathers for block k+1 issued before consuming block k
// -> 16 loads in flight (compiler emits vmcnt(8)-style waits, not full drains).
template<int CH, bool BR>
__global__ __launch_bounds__(256) void agg_h_kernel(const float* __restrict__ src,
                                                    const int2* __restrict__ csr,
                                                    const int4* __restrict__ rowdesc,
                                                    const float* __restrict__ bias,
                                                    float* __restrict__ dst, int half) {
  int b = blockIdx.x & 7;
  int chunk = blockIdx.x >> 3;
  int wave = threadIdx.x >> 6, lane = threadIdx.x & 63;
  int d = chunk * 4 + wave;
  if (d >= N_G) return;
  d = __builtin_amdgcn_readfirstlane(d);
  int4 rd = rowdesc[d];                  // one s_load_dwordx4 prologue
  int e0 = rd.x, n = rd.y;
  float dv = __int_as_float(rd.z);
  int c = (CH == 128) ? ((half << 6) + lane) : lane;
  const float* sb = src + (size_t)b * N_G * CH;
  const int2* ce = csr + e0;
  float acc[8];
  acc[0] = dv * sb[(size_t)d * CH + c];
#pragma unroll
  for (int k = 1; k < 8; ++k) acc[k] = 0.f;
  int l = 0;
  if (n >= 8) {
    int2 pA[8]; float vA[8];
#pragma unroll
    for (int k = 0; k < 8; ++k) pA[k] = ce[k];
#pragma unroll
    for (int k = 0; k < 8; ++k) vA[k] = sb[(size_t)pA[k].x * CH + c];
    l = 8;
    for (; l + 8 <= n; l += 8) {
      int2 pB[8]; float vB[8];
#pragma unroll
      for (int k = 0; k < 8; ++k) pB[k] = ce[l + k];
#pragma unroll
      for (int k = 0; k < 8; ++k) vB[k] = sb[(size_t)pB[k].x * CH + c];
#pragma unroll
      for (int k = 0; k < 8; ++k) acc[k] = fmaf(__int_as_float(pA[k].y), vA[k], acc[k]);
#pragma unroll
      for (int k = 0; k < 8; ++k) { pA[k] = pB[k]; vA[k] = vB[k]; }
    }
#pragma unroll
    for (int k = 0; k < 8; ++k) acc[k] = fmaf(__int_as_float(pA[k].y), vA[k], acc[k]);
  }
  for (; l < n; ++l) {
    int2 p = ce[l];
    acc[0] = fmaf(__int_as_float(p.y), sb[(size_t)p.x * CH + c], acc[0]);
  }
  float s = ((acc[0] + acc[1]) + (acc[2] + acc[3])) + ((acc[4] + acc[5]) + (acc[6] + acc[7]));
  float r = BR ? fmaxf(fmaf(dv, s, bias[c]), 0.f) : dv * s;
  __builtin_nontemporal_store(r, &dst[((size_t)b * N_G + d) * CH + c]);
}

// ---------------- layer-3 half-agg fused with partial score/fc dots ----------------
__global__ __launch_bounds__(256) void agg_score_h_kernel(const float* __restrict__ hw,
                                                          const int2* __restrict__ csr,
                                                          const int4* __restrict__ rowdesc,
                                                          const float* __restrict__ bias,
                                                          const float* __restrict__ h1,
                                                          const float* __restrict__ h2,
                                                          const float* __restrict__ topk_w,
                                                          const float* __restrict__ fcW,
                                                          float* __restrict__ pd1,
                                                          float* __restrict__ pd2, int half) {
  int b = blockIdx.x & 7;
  int chunk = blockIdx.x >> 3;
  int wave = threadIdx.x >> 6, lane = threadIdx.x & 63;
  int d = chunk * 4 + wave;
  if (d >= N_G) return;
  d = __builtin_amdgcn_readfirstlane(d);
  int4 rd = rowdesc[d];
  int e0 = rd.x, n = rd.y;
  float dv = __int_as_float(rd.z);
  int c = (half << 6) + lane;
  const float* sb = hw + (size_t)b * N_G * NH;
  const int2* ce = csr + e0;
  // prefetch the compulsory-HBM h1/h2 row elements so their latency overlaps the loop
  size_t rbase = ((size_t)b * N_G + d) * NH + c;
  float u1 = __builtin_nontemporal_load(h1 + rbase);
  float u2 = __builtin_nontemporal_load(h2 + rbase);
  float acc[8];
  acc[0] = dv * sb[(size_t)d * NH + c];
#pragma unroll
  for (int k = 1; k < 8; ++k) acc[k] = 0.f;
  int l = 0;
  if (n >= 8) {
    int2 pA[8]; float vA[8];
#pragma unroll
    for (int k = 0; k < 8; ++k) pA[k] = ce[k];
#pragma unroll
    for (int k = 0; k < 8; ++k) vA[k] = sb[(size_t)pA[k].x * NH + c];
    l = 8;
    for (; l + 8 <= n; l += 8) {
      int2 pB[8]; float vB[8];
#pragma unroll
      for (int k = 0; k < 8; ++k) pB[k] = ce[l + k];
#pragma unroll
      for (int k = 0; k < 8; ++k) vB[k] = sb[(size_t)pB[k].x * NH + c];
#pragma unroll
      for (int k = 0; k < 8; ++k) acc[k] = fmaf(__int_as_float(pA[k].y), vA[k], acc[k]);
#pragma unroll
      for (int k = 0; k < 8; ++k) { pA[k] = pB[k]; vA[k] = vB[k]; }
    }
#pragma unroll
    for (int k = 0; k < 8; ++k) acc[k] = fmaf(__int_as_float(pA[k].y), vA[k], acc[k]);
  }
  for (; l < n; ++l) {
    int2 p = ce[l];
    acc[0] = fmaf(__int_as_float(p.y), sb[(size_t)p.x * NH + c], acc[0]);
  }
  float s = ((acc[0] + acc[1]) + (acc[2] + acc[3])) + ((acc[4] + acc[5]) + (acc[6] + acc[7]));
  float r = fmaxf(fmaf(dv, s, bias[c]), 0.f);
  // fused partial dots, xc feature order f = c*3 + layer
  float d1 = u1 * topk_w[c * 3] + u2 * topk_w[c * 3 + 1] + r * topk_w[c * 3 + 2];
  float d2 = u1 * fcW[c * 3]    + u2 * fcW[c * 3 + 1]    + r * fcW[c * 3 + 2];
#pragma unroll
  for (int sh = 32; sh > 0; sh >>= 1) {
    d1 += __shfl_down(d1, sh);
    d2 += __shfl_down(d2, sh);
  }
  if (lane == 0) {
    int gw = b * N_G + d;
    pd1[gw * 2 + half] = d1;
    pd2[gw * 2 + half] = d2;
  }
}

// ---------------- combine halves -> score/key + histogram ----------------
__global__ void combine_kernel(const float* __restrict__ pd1, const float* __restrict__ pd2,
                               const float* __restrict__ scal, float* __restrict__ score,
                               float* __restrict__ d2a, unsigned* __restrict__ keys,
                               int* __restrict__ hist) {
  int b = blockIdx.y;
  int i = blockIdx.x * 256 + threadIdx.x;
  if (i >= N_G) return;
  int gw = b * N_G + i;
  float d1 = pd1[2 * gw] + pd1[2 * gw + 1];
  float d2 = pd2[2 * gw] + pd2[2 * gw + 1];
  float sc = tanhf(d1 * scal[0]);
  score[gw] = sc;
  d2a[gw] = d2;
  unsigned u = __float_as_uint(sc);
  unsigned k32 = (u & 0x80000000u) ? ~u : (u | 0x80000000u);
  keys[gw] = k32;
  atomicAdd(&hist[b * NBIN + (int)(k32 >> 16)], 1);
}

// ---------------- per-batch suffix sums over 65536 bins ----------------
__global__ __launch_bounds__(1024) void suffix_kernel(const int* __restrict__ hist,
                                                      int* __restrict__ suf) {
  __shared__ int buf[1024];
  int b = blockIdx.x;
  const int* hb = hist + b * NBIN;
  int* sb = suf + b * SUFS;
  int t = threadIdx.x;
  int base = t * 64;
  int s = 0;
  for (int k = 0; k < 64; ++k) s += hb[base + k];
  buf[t] = s;
  __syncthreads();
  for (int off = 1; off < 1024; off <<= 1) {
    int v = (t + off < 1024) ? buf[t + off] : 0;
    __syncthreads();
    buf[t] += v;
    __syncthreads();
  }
  int acc = buf[t] - s;
  if (t == 0) sb[NBIN] = 0;
  for (int k = 63; k >= 0; --k) {
    acc += hb[base + k];
    sb[base + k] = acc;
  }
}

// ---------------- bucket scatter (consumes hist via atomicSub) ----------------
__global__ void scatter_kernel(const unsigned* __restrict__ keys, int* __restrict__ hist,
                               const int* __restrict__ suf, int2* __restrict__ bucket) {
  int b = blockIdx.y;
  int i = blockIdx.x * 256 + threadIdx.x;
  if (i >= N_G) return;
  unsigned k = keys[b * N_G + i];
  int bin = (int)(k >> 16);
  int old = atomicSub(&hist[b * NBIN + bin], 1);
  int pos = suf[b * SUFS + bin + 1] + old - 1;
  bucket[b * N_G + pos] = make_int2((int)k, i);
}

// ---------------- exact stable-descending rank + z scatter ----------------
__global__ void rank_z_kernel(const unsigned* __restrict__ keys, const int* __restrict__ suf,
                              const int2* __restrict__ bucket, const float* __restrict__ score,
                              const float* __restrict__ d2a, const float* __restrict__ fcb,
                              float* __restrict__ z) {
  int b = blockIdx.y;
  int i = blockIdx.x * 256 + threadIdx.x;
  if (i >= N_G) return;
  int gw = b * N_G + i;
  unsigned k = keys[gw];
  int bin = (int)(k >> 16);
  int lo = suf[b * SUFS + bin + 1];
  int hi = suf[b * SUFS + bin];
  int r = lo;
  const int2* bk = bucket + b * N_G;
  for (int p = lo; p < hi; ++p) {
    int2 e = bk[p];
    unsigned kj = (unsigned)e.x;
    r += (kj > k || (kj == k && e.y < i)) ? 1 : 0;
  }
  if (r < K_TOP) z[b * K_TOP + r] = fmaf(score[gw], d2a[gw], fcb[0]);
}

// ---------------- lin1 ----------------
__global__ __launch_bounds__(256) void lin1_kernel(const float* __restrict__ z,
                                                   const float* __restrict__ W,
                                                   float* __restrict__ hpre) {
  __shared__ float zb[237];
  int b = blockIdx.y, rs = blockIdx.x;
  int r0 = rs * 237;
  int rn = K_TOP - r0; if (rn > 237) rn = 237;
  for (int q = threadIdx.x; q < rn; q += 256) zb[q] = z[b * K_TOP + r0 + q];
  __syncthreads();
  int c = threadIdx.x;
  float a0 = 0.f, a1 = 0.f;
  for (int r = 0; r < rn; ++r) {
    float zz = zb[r];
    const float* wr = W + (size_t)(r0 + r) * 512;
    a0 = fmaf(zz, wr[c], a0);
    a1 = fmaf(zz, wr[c + 256], a1);
  }
  atomicAdd(&hpre[b * 512 + c], a0);
  atomicAdd(&hpre[b * 512 + c + 256], a1);
}

// ---------------- lin2 + log_softmax ----------------
__global__ __launch_bounds__(128) void lin2_kernel(const float* __restrict__ hpre,
                                                   const float* __restrict__ l1b,
                                                   const float* __restrict__ W2,
                                                   const float* __restrict__ l2b,
                                                   float* __restrict__ out) {
  int b = blockIdx.x, tid = threadIdx.x;
  float a0 = 0.f, a1 = 0.f;
  for (int j = tid; j < 512; j += 128) {
    float t = fmaxf(hpre[b * 512 + j] + l1b[j], 0.f);
    a0 = fmaf(t, W2[j * 2 + 0], a0);
    a1 = fmaf(t, W2[j * 2 + 1], a1);
  }
#pragma unroll
  for (int s = 32; s > 0; s >>= 1) {
    a0 += __shfl_down(a0, s);
    a1 += __shfl_down(a1, s);
  }
  __shared__ float red[2][2];
  if ((tid & 63) == 0) { red[tid >> 6][0] = a0; red[tid >> 6][1] = a1; }
  __syncthreads();
  if (tid == 0) {
    float l0 = red[0][0] + red[1][0] + l2b[0];
    float l1 = red[0][1] + red[1][1] + l2b[1];
    float m = fmaxf(l0, l1);
    float lse = m + logf(expf(l0 - m) + expf(l1 - m));
    out[b * 2 + 0] = l0 - lse;
    out[b * 2 + 1] = l1 - lse;
  }
}

extern "C" void kernel_launch(void* const* d_in, const int* in_sizes, int n_in,
                              void* d_out, int out_size, void* d_ws, size_t ws_size,
                              hipStream_t stream) {
  const float* x   = (const float*)d_in[0];
  const int*   ei  = (const int*)d_in[2];
  const float* W1  = (const float*)d_in[3];
  const float* b1  = (const float*)d_in[4];
  const float* W2  = (const float*)d_in[5];
  const float* b2  = (const float*)d_in[6];
  const float* W3  = (const float*)d_in[7];
  const float* b3  = (const float*)d_in[8];
  const float* tkw = (const float*)d_in[9];
  const float* fcW = (const float*)d_in[10];
  const float* fcb = (const float*)d_in[11];
  const float* l1W = (const float*)d_in[12];
  const float* l1b = (const float*)d_in[13];
  const float* l2W = (const float*)d_in[14];
  const float* l2b = (const float*)d_in[15];
  float* out = (float*)d_out;

  char* ws = (char*)d_ws;
  size_t off = 0;
  auto alloc = [&](size_t bytes) {
    char* p = ws + off;
    off += (bytes + 255) & ~(size_t)255;
    return p;
  };
  // zero-init region (contiguous): cnt, fillc, gctr, hpre, hist
  int*   cnt   = (int*)alloc(15136 * 4);
  int*   fillc = (int*)alloc(15136 * 4);
  int*   gctr  = (int*)alloc(256);
  float* hpre  = (float*)alloc(4096 * 4);
  int*   hist  = (int*)alloc((size_t)BSZ * NBIN * 4);
  // --- end zero region ---
  int*   rowstart = (int*)alloc(15136 * 4);
  float* dinv  = (float*)alloc(15136 * 4);
  int4*  rowdesc = (int4*)alloc(15136 * 16);
  float* scal  = (float*)alloc(64);
  float* z     = (float*)alloc((size_t)BSZ * K_TOP * 4);
  float* score = (float*)alloc(121088 * 4);
  float* d2a   = (float*)alloc(121088 * 4);
  unsigned* keys = (unsigned*)alloc(121088 * 4);
  int*   suf   = (int*)alloc((size_t)BSZ * SUFS * 4);
  int2*  bucket = (int2*)alloc(121088 * 8);
  float* pd1   = (float*)alloc(121088 * 2 * 4);
  float* pd2   = (float*)alloc(121088 * 2 * 4);
  int2*  csr   = (int2*)alloc((size_t)E_N * 8);
  float* ax = (float*)alloc((size_t)BSZ * N_G * 64 * 4);
  float* hw = (float*)alloc((size_t)BSZ * N_G * NH * 4);
  float* h1 = (float*)alloc((size_t)BSZ * N_G * NH * 4);
  float* h2 = (float*)alloc((size_t)BSZ * N_G * NH * 4);
  (void)ws_size; (void)in_sizes; (void)n_in; (void)out_size;

  int zero_n = (int)(((char*)rowstart - (char*)cnt) / 4);
  zero_kernel<<<(zero_n + 1023) / 1024, 1024, 0, stream>>>(cnt, zero_n);
  count_kernel<<<(E_N + 255) / 256, 256, 0, stream>>>(ei, cnt);
  scan_kernel<<<(N_G + 1023) / 1024, 1024, 0, stream>>>(cnt, rowstart, dinv, rowdesc, gctr, tkw, scal);
  fill_kernel<<<(E_N + 255) / 256, 256, 0, stream>>>(ei, rowstart, dinv, fillc, csr);

  dim3 mmg(8 * 237);  // batch-pinned: b = blk&7
  int aggblocks = 8 * ((N_G + 3) / 4);

  // layer 1: agg(x) @ W1 (commutation)
  agg_h_kernel<64, false><<<aggblocks, 256, 0, stream>>>(x, csr, rowdesc, nullptr, ax, 0);
  mm_kernel<64, true><<<mmg, 256, 0, stream>>>(ax, W1, b1, h1);
  // layer 2
  mm_kernel<128, false><<<mmg, 256, 0, stream>>>(h1, W2, nullptr, hw);
  agg_h_kernel<128, true><<<aggblocks, 256, 0, stream>>>(hw, csr, rowdesc, b2, h2, 0);
  agg_h_kernel<128, true><<<aggblocks, 256, 0, stream>>>(hw, csr, rowdesc, b2, h2, 1);
  // layer 3 fused with score partials
  mm_kernel<128, false><<<mmg, 256, 0, stream>>>(h2, W3, nullptr, hw);
  agg_score_h_kernel<<<aggblocks, 256, 0, stream>>>(hw, csr, rowdesc, b3,
                                                    h1, h2, tkw, fcW, pd1, pd2, 0);
  agg_score_h_kernel<<<aggblocks, 256, 0, stream>>>(hw, csr, rowdesc, b3,
                                                    h1, h2, tkw, fcW, pd1, pd2, 1);

  dim3 ng((N_G + 255) / 256, BSZ);
  combine_kernel<<<ng, 256, 0, stream>>>(pd1, pd2, scal, score, d2a, keys, hist);
  suffix_kernel<<<BSZ, 1024, 0, stream>>>(hist, suf);
  scatter_kernel<<<ng, 256, 0, stream>>>(keys, hist, suf, bucket);
  rank_z_kernel<<<ng, 256, 0, stream>>>(keys, suf, bucket, score, d2a, fcb, z);

  dim3 l1g(32, BSZ);
  lin1_kernel<<<l1g, 256, 0, stream>>>(z, l1W, hpre);
  lin2_kernel<<<BSZ, 128, 0, stream>>>(hpre, l1b, l2W, l2b, out);
}

// Round 12
// 615.056 us; speedup vs baseline: 1.7327x; 1.0786x over previous
//
#include <hip/hip_runtime.h>

#define N_G   15135
#define E_N   242160
#define BSZ   8
#define K_TOP 7568
#define NH    128
#define NBIN  65536
#define SUFS  65600

typedef float f4v __attribute__((ext_vector_type(4)));
typedef float f2v __attribute__((ext_vector_type(2)));

// ---------------- utility ----------------
__global__ void zero_kernel(int* __restrict__ p, int n) {
  int i = blockIdx.x * 1024 + threadIdx.x;
  if (i < n) p[i] = 0;
}

__global__ void count_kernel(const int* __restrict__ ei, int* __restrict__ cnt) {
  int e = blockIdx.x * 256 + threadIdx.x;
  if (e < E_N) atomicAdd(&cnt[ei[E_N + e]], 1);
}

// local scan + atomic ticket; emits dinv, packed row descriptor (rowstart,cnt,dinv), scal.
__global__ __launch_bounds__(1024) void scan_kernel(const int* __restrict__ cnt,
                                                    int* __restrict__ rowstart,
                                                    float* __restrict__ dinv,
                                                    int4* __restrict__ rowdesc,
                                                    int* __restrict__ gctr,
                                                    const float* __restrict__ topk_w,
                                                    float* __restrict__ scal) {
  __shared__ int buf[1024];
  __shared__ int base;
  int tid = threadIdx.x;
  int i = blockIdx.x * 1024 + tid;
  int v = (i < N_G) ? cnt[i] : 0;
  float di = 1.0f / sqrtf((float)(v + 1));
  if (i < N_G) dinv[i] = di;
  buf[tid] = v;
  __syncthreads();
  for (int s = 1; s < 1024; s <<= 1) {
    int t = (tid >= s) ? buf[tid - s] : 0;
    __syncthreads();
    buf[tid] += t;
    __syncthreads();
  }
  if (tid == 1023) base = atomicAdd(gctr, buf[1023]);
  __syncthreads();
  if (i < N_G) {
    int rs = base + buf[tid] - v;
    rowstart[i] = rs;
    rowdesc[i] = make_int4(rs, v, __float_as_int(di), 0);
  }
  if (blockIdx.x == 0) {
    __shared__ float fbuf[512];
    if (tid < 512) {
      float w = (tid < 384) ? topk_w[tid] : 0.f;
      fbuf[tid] = w * w;
    }
    __syncthreads();
    for (int s = 256; s > 0; s >>= 1) {
      if (tid < s) fbuf[tid] += fbuf[tid + s];
      __syncthreads();
    }
    if (tid == 0) scal[0] = 1.0f / sqrtf(fbuf[0]);
  }
}

// csr packs (src, dinv[src]).
__global__ void fill_kernel(const int* __restrict__ ei, const int* __restrict__ rowstart,
                            const float* __restrict__ dinv, int* __restrict__ fillc,
                            int2* __restrict__ csr) {
  int e = blockIdx.x * 256 + threadIdx.x;
  if (e < E_N) {
    int s = ei[e], d = ei[E_N + e];
    int pos = rowstart[d] + atomicAdd(&fillc[d], 1);
    csr[pos] = make_int2(s, __float_as_int(dinv[s]));
  }
}

// ---------------- dense matmul, batch-pinned blocks ----------------
template<int CIN, bool BR>
__global__ __launch_bounds__(256, 6) void mm_kernel(const float* __restrict__ A,
                                                    const float* __restrict__ W,
                                                    const float* __restrict__ bias,
                                                    float* __restrict__ out) {
  __shared__ float Bst[32][132];
  __shared__ float Ast2[32][68];
  int tid = threadIdx.x;
  int b = blockIdx.x & 7;
  int ib = blockIdx.x >> 3;
  int rb0 = b * N_G + ib * 64;
  int rmax = N_G - ib * 64;
  int c0 = (tid & 31) * 4;
  int r0 = (tid >> 5) * 8;
  float acc[8][4];
#pragma unroll
  for (int i = 0; i < 8; i++)
#pragma unroll
    for (int j = 0; j < 4; j++) acc[i][j] = 0.f;

  for (int k0 = 0; k0 < CIN; k0 += 32) {
    {
      int koff = (tid & 7) * 4;
      int row = tid >> 3;
#pragma unroll
      for (int p = 0; p < 2; ++p) {
        int r = row + p * 32;
        f4v v = {0.f, 0.f, 0.f, 0.f};
        if (r < rmax) v = __builtin_nontemporal_load((const f4v*)(A + (size_t)(rb0 + r) * CIN + k0 + koff));
        Ast2[koff + 0][r] = v.x; Ast2[koff + 1][r] = v.y;
        Ast2[koff + 2][r] = v.z; Ast2[koff + 3][r] = v.w;
      }
    }
    {
      int cc = (tid & 31) * 4;
      int kr = tid >> 5;
#pragma unroll
      for (int p = 0; p < 4; ++p) {
        int k = kr + p * 8;
        *(float4*)&Bst[k][cc] = *(const float4*)(W + (size_t)(k0 + k) * NH + cc);
      }
    }
    __syncthreads();
#pragma unroll 4
    for (int kk = 0; kk < 32; ++kk) {
      float a[8], bb[4];
      *(float4*)&a[0] = *(const float4*)&Ast2[kk][r0];
      *(float4*)&a[4] = *(const float4*)&Ast2[kk][r0 + 4];
      *(float4*)&bb[0] = *(const float4*)&Bst[kk][c0];
#pragma unroll
      for (int i = 0; i < 8; i++)
#pragma unroll
        for (int j = 0; j < 4; j++)
          acc[i][j] = fmaf(a[i], bb[j], acc[i][j]);
    }
    __syncthreads();
  }
  float b0 = 0.f, b1 = 0.f, b2 = 0.f, b3 = 0.f;
  if (BR) { b0 = bias[c0]; b1 = bias[c0+1]; b2 = bias[c0+2]; b3 = bias[c0+3]; }
#pragma unroll
  for (int i = 0; i < 8; i++) {
    int r = r0 + i;
    if (r < rmax) {
      float4 v;
      if (BR) {
        v.x = fmaxf(acc[i][0] + b0, 0.f); v.y = fmaxf(acc[i][1] + b1, 0.f);
        v.z = fmaxf(acc[i][2] + b2, 0.f); v.w = fmaxf(acc[i][3] + b3, 0.f);
      } else {
        v.x = acc[i][0]; v.y = acc[i][1]; v.z = acc[i][2]; v.w = acc[i][3];
      }
      *(float4*)(out + (size_t)(rb0 + r) * NH + c0) = v;
    }
  }
}

// ---------------- x-aggregation (64 ch, float1 lanes), pipelined ----------------
__global__ __launch_bounds__(256) void agg64_kernel(const float* __restrict__ src,
                                                    const int2* __restrict__ csr,
                                                    const int4* __restrict__ rowdesc,
                                                    float* __restrict__ dst) {
  int b = blockIdx.x & 7;
  int chunk = blockIdx.x >> 3;
  int wave = threadIdx.x >> 6, lane = threadIdx.x & 63;
  int d = chunk * 4 + wave;
  if (d >= N_G) return;
  d = __builtin_amdgcn_readfirstlane(d);
  int4 rd = rowdesc[d];
  int e0 = rd.x, n = rd.y;
  float dv = __int_as_float(rd.z);
  const float* sb = src + (size_t)b * N_G * 64;
  const int2* ce = csr + e0;
  float acc[8];
  acc[0] = dv * sb[(size_t)d * 64 + lane];
#pragma unroll
  for (int k = 1; k < 8; ++k) acc[k] = 0.f;
  int l = 0;
  if (n >= 8) {
    int2 pA[8]; float vA[8];
#pragma unroll
    for (int k = 0; k < 8; ++k) pA[k] = ce[k];
#pragma unroll
    for (int k = 0; k < 8; ++k) vA[k] = sb[(size_t)pA[k].x * 64 + lane];
    l = 8;
    for (; l + 8 <= n; l += 8) {
      int2 pB[8]; float vB[8];
#pragma unroll
      for (int k = 0; k < 8; ++k) pB[k] = ce[l + k];
#pragma unroll
      for (int k = 0; k < 8; ++k) vB[k] = sb[(size_t)pB[k].x * 64 + lane];
#pragma unroll
      for (int k = 0; k < 8; ++k) acc[k] = fmaf(__int_as_float(pA[k].y), vA[k], acc[k]);
#pragma unroll
      for (int k = 0; k < 8; ++k) { pA[k] = pB[k]; vA[k] = vB[k]; }
    }
#pragma unroll
    for (int k = 0; k < 8; ++k) acc[k] = fmaf(__int_as_float(pA[k].y), vA[k], acc[k]);
  }
  for (; l < n; ++l) {
    int2 p = ce[l];
    acc[0] = fmaf(__int_as_float(p.y), sb[(size_t)p.x * 64 + lane], acc[0]);
  }
  float s = ((acc[0] + acc[1]) + (acc[2] + acc[3])) + ((acc[4] + acc[5]) + (acc[6] + acc[7]));
  __builtin_nontemporal_store(dv * s, &dst[((size_t)b * N_G + d) * 64 + lane]);
}

// ---------------- full-width aggregation (128 ch, float2 lanes), pipelined -------------
// One wave per row, lane covers channels (2l, 2l+1): each gather = one 512-B segment.
__global__ __launch_bounds__(256) void agg_f2_kernel(const float* __restrict__ hw,
                                                     const int2* __restrict__ csr,
                                                     const int4* __restrict__ rowdesc,
                                                     const float* __restrict__ bias,
                                                     float* __restrict__ hout) {
  int b = blockIdx.x & 7;
  int chunk = blockIdx.x >> 3;
  int wave = threadIdx.x >> 6, lane = threadIdx.x & 63;
  int d = chunk * 4 + wave;
  if (d >= N_G) return;
  d = __builtin_amdgcn_readfirstlane(d);
  int4 rd = rowdesc[d];
  int e0 = rd.x, n = rd.y;
  float dv = __int_as_float(rd.z);
  const f2v* sb = (const f2v*)(hw + (size_t)b * N_G * NH);
  const int2* ce = csr + e0;
  f2v self = sb[(size_t)d * 64 + lane];
  float ax[4], ay[4];
  ax[0] = dv * self.x; ay[0] = dv * self.y;
#pragma unroll
  for (int k = 1; k < 4; ++k) { ax[k] = 0.f; ay[k] = 0.f; }
  int l = 0;
  if (n >= 8) {
    int2 pA[8]; f2v vA[8];
#pragma unroll
    for (int k = 0; k < 8; ++k) pA[k] = ce[k];
#pragma unroll
    for (int k = 0; k < 8; ++k) vA[k] = sb[(size_t)pA[k].x * 64 + lane];
    l = 8;
    for (; l + 8 <= n; l += 8) {
      int2 pB[8]; f2v vB[8];
#pragma unroll
      for (int k = 0; k < 8; ++k) pB[k] = ce[l + k];
#pragma unroll
      for (int k = 0; k < 8; ++k) vB[k] = sb[(size_t)pB[k].x * 64 + lane];
#pragma unroll
      for (int k = 0; k < 8; ++k) {
        float w = __int_as_float(pA[k].y);
        ax[k & 3] = fmaf(w, vA[k].x, ax[k & 3]);
        ay[k & 3] = fmaf(w, vA[k].y, ay[k & 3]);
      }
#pragma unroll
      for (int k = 0; k < 8; ++k) { pA[k] = pB[k]; vA[k] = vB[k]; }
    }
#pragma unroll
    for (int k = 0; k < 8; ++k) {
      float w = __int_as_float(pA[k].y);
      ax[k & 3] = fmaf(w, vA[k].x, ax[k & 3]);
      ay[k & 3] = fmaf(w, vA[k].y, ay[k & 3]);
    }
  }
  for (; l < n; ++l) {
    int2 p = ce[l];
    f2v v = sb[(size_t)p.x * 64 + lane];
    float w = __int_as_float(p.y);
    ax[0] = fmaf(w, v.x, ax[0]); ay[0] = fmaf(w, v.y, ay[0]);
  }
  float sx = (ax[0] + ax[1]) + (ax[2] + ax[3]);
  float sy = (ay[0] + ay[1]) + (ay[2] + ay[3]);
  const f2v* bb2 = (const f2v*)bias;
  f2v bb = bb2[lane];
  f2v r;
  r.x = fmaxf(fmaf(dv, sx, bb.x), 0.f);
  r.y = fmaxf(fmaf(dv, sy, bb.y), 0.f);
  __builtin_nontemporal_store(r, &((f2v*)hout)[((size_t)b * N_G + d) * 64 + lane]);
}

// ---------------- layer-3 full-width agg fused with score/fc dots + key + hist --------
// Channel pair (2l,2l+1) -> xc features 6l..6l+5 (f = h*3 + layer). Absorbs combine.
__global__ __launch_bounds__(256) void agg_score_f2_kernel(const float* __restrict__ hw,
                                                           const int2* __restrict__ csr,
                                                           const int4* __restrict__ rowdesc,
                                                           const float* __restrict__ bias,
                                                           const float* __restrict__ h1,
                                                           const float* __restrict__ h2,
                                                           const float* __restrict__ topk_w,
                                                           const float* __restrict__ fcW,
                                                           const float* __restrict__ scal,
                                                           float* __restrict__ score,
                                                           float* __restrict__ d2a,
                                                           unsigned* __restrict__ keys,
                                                           int* __restrict__ hist) {
  int b = blockIdx.x & 7;
  int chunk = blockIdx.x >> 3;
  int wave = threadIdx.x >> 6, lane = threadIdx.x & 63;
  int d = chunk * 4 + wave;
  if (d >= N_G) return;
  d = __builtin_amdgcn_readfirstlane(d);
  int4 rd = rowdesc[d];
  int e0 = rd.x, n = rd.y;
  float dv = __int_as_float(rd.z);
  const f2v* sb = (const f2v*)(hw + (size_t)b * N_G * NH);
  const int2* ce = csr + e0;
  // prefetch compulsory-HBM h1/h2 pairs early so the miss overlaps the loop
  size_t rbase = ((size_t)b * N_G + d) * 64 + lane;
  f2v u1 = __builtin_nontemporal_load(&((const f2v*)h1)[rbase]);
  f2v u2 = __builtin_nontemporal_load(&((const f2v*)h2)[rbase]);
  f2v self = sb[(size_t)d * 64 + lane];
  float ax[4], ay[4];
  ax[0] = dv * self.x; ay[0] = dv * self.y;
#pragma unroll
  for (int k = 1; k < 4; ++k) { ax[k] = 0.f; ay[k] = 0.f; }
  int l = 0;
  if (n >= 8) {
    int2 pA[8]; f2v vA[8];
#pragma unroll
    for (int k = 0; k < 8; ++k) pA[k] = ce[k];
#pragma unroll
    for (int k = 0; k < 8; ++k) vA[k] = sb[(size_t)pA[k].x * 64 + lane];
    l = 8;
    for (; l + 8 <= n; l += 8) {
      int2 pB[8]; f2v vB[8];
#pragma unroll
      for (int k = 0; k < 8; ++k) pB[k] = ce[l + k];
#pragma unroll
      for (int k = 0; k < 8; ++k) vB[k] = sb[(size_t)pB[k].x * 64 + lane];
#pragma unroll
      for (int k = 0; k < 8; ++k) {
        float w = __int_as_float(pA[k].y);
        ax[k & 3] = fmaf(w, vA[k].x, ax[k & 3]);
        ay[k & 3] = fmaf(w, vA[k].y, ay[k & 3]);
      }
#pragma unroll
      for (int k = 0; k < 8; ++k) { pA[k] = pB[k]; vA[k] = vB[k]; }
    }
#pragma unroll
    for (int k = 0; k < 8; ++k) {
      float w = __int_as_float(pA[k].y);
      ax[k & 3] = fmaf(w, vA[k].x, ax[k & 3]);
      ay[k & 3] = fmaf(w, vA[k].y, ay[k & 3]);
    }
  }
  for (; l < n; ++l) {
    int2 p = ce[l];
    f2v v = sb[(size_t)p.x * 64 + lane];
    float w = __int_as_float(p.y);
    ax[0] = fmaf(w, v.x, ax[0]); ay[0] = fmaf(w, v.y, ay[0]);
  }
  float sx = (ax[0] + ax[1]) + (ax[2] + ax[3]);
  float sy = (ay[0] + ay[1]) + (ay[2] + ay[3]);
  const f2v* bb2 = (const f2v*)bias;
  f2v bb = bb2[lane];
  float rx = fmaxf(fmaf(dv, sx, bb.x), 0.f);
  float ry = fmaxf(fmaf(dv, sy, bb.y), 0.f);
  // fused dots (verified mapping from R2/R3): features 6l..6l+5
  const f2v* tw2 = (const f2v*)topk_w;
  const f2v* fw2 = (const f2v*)fcW;
  f2v ta = tw2[lane * 3 + 0], tb = tw2[lane * 3 + 1], tc = tw2[lane * 3 + 2];
  f2v fa = fw2[lane * 3 + 0], fb = fw2[lane * 3 + 1], fc = fw2[lane * 3 + 2];
  float d1 = u1.x * ta.x + u2.x * ta.y + rx * tb.x
           + u1.y * tb.y + u2.y * tc.x + ry * tc.y;
  float d2 = u1.x * fa.x + u2.x * fa.y + rx * fb.x
           + u1.y * fb.y + u2.y * fc.x + ry * fc.y;
#pragma unroll
  for (int sh = 32; sh > 0; sh >>= 1) {
    d1 += __shfl_down(d1, sh);
    d2 += __shfl_down(d2, sh);
  }
  if (lane == 0) {
    int gw = b * N_G + d;
    float sc = tanhf(d1 * scal[0]);
    score[gw] = sc;
    d2a[gw] = d2;
    unsigned u = __float_as_uint(sc);
    unsigned k32 = (u & 0x80000000u) ? ~u : (u | 0x80000000u);
    keys[gw] = k32;
    atomicAdd(&hist[b * NBIN + (int)(k32 >> 16)], 1);
  }
}

// ---------------- per-batch suffix sums over 65536 bins ----------------
__global__ __launch_bounds__(1024) void suffix_kernel(const int* __restrict__ hist,
                                                      int* __restrict__ suf) {
  __shared__ int buf[1024];
  int b = blockIdx.x;
  const int* hb = hist + b * NBIN;
  int* sb = suf + b * SUFS;
  int t = threadIdx.x;
  int base = t * 64;
  int s = 0;
  for (int k = 0; k < 64; ++k) s += hb[base + k];
  buf[t] = s;
  __syncthreads();
  for (int off = 1; off < 1024; off <<= 1) {
    int v = (t + off < 1024) ? buf[t + off] : 0;
    __syncthreads();
    buf[t] += v;
    __syncthreads();
  }
  int acc = buf[t] - s;
  if (t == 0) sb[NBIN] = 0;
  for (int k = 63; k >= 0; --k) {
    acc += hb[base + k];
    sb[base + k] = acc;
  }
}

// ---------------- bucket scatter (consumes hist via atomicSub) ----------------
__global__ void scatter_kernel(const unsigned* __restrict__ keys, int* __restrict__ hist,
                               const int* __restrict__ suf, int2* __restrict__ bucket) {
  int b = blockIdx.y;
  int i = blockIdx.x * 256 + threadIdx.x;
  if (i >= N_G) return;
  unsigned k = keys[b * N_G + i];
  int bin = (int)(k >> 16);
  int old = atomicSub(&hist[b * NBIN + bin], 1);
  int pos = suf[b * SUFS + bin + 1] + old - 1;
  bucket[b * N_G + pos] = make_int2((int)k, i);
}

// ---------------- exact stable-descending rank + z scatter ----------------
__global__ void rank_z_kernel(const unsigned* __restrict__ keys, const int* __restrict__ suf,
                              const int2* __restrict__ bucket, const float* __restrict__ score,
                              const float* __restrict__ d2a, const float* __restrict__ fcb,
                              float* __restrict__ z) {
  int b = blockIdx.y;
  int i = blockIdx.x * 256 + threadIdx.x;
  if (i >= N_G) return;
  int gw = b * N_G + i;
  unsigned k = keys[gw];
  int bin = (int)(k >> 16);
  int lo = suf[b * SUFS + bin + 1];
  int hi = suf[b * SUFS + bin];
  int r = lo;
  const int2* bk = bucket + b * N_G;
  for (int p = lo; p < hi; ++p) {
    int2 e = bk[p];
    unsigned kj = (unsigned)e.x;
    r += (kj > k || (kj == k && e.y < i)) ? 1 : 0;
  }
  if (r < K_TOP) z[b * K_TOP + r] = fmaf(score[gw], d2a[gw], fcb[0]);
}

// ---------------- lin1 ----------------
__global__ __launch_bounds__(256) void lin1_kernel(const float* __restrict__ z,
                                                   const float* __restrict__ W,
                                                   float* __restrict__ hpre) {
  __shared__ float zb[237];
  int b = blockIdx.y, rs = blockIdx.x;
  int r0 = rs * 237;
  int rn = K_TOP - r0; if (rn > 237) rn = 237;
  for (int q = threadIdx.x; q < rn; q += 256) zb[q] = z[b * K_TOP + r0 + q];
  __syncthreads();
  int c = threadIdx.x;
  float a0 = 0.f, a1 = 0.f;
  for (int r = 0; r < rn; ++r) {
    float zz = zb[r];
    const float* wr = W + (size_t)(r0 + r) * 512;
    a0 = fmaf(zz, wr[c], a0);
    a1 = fmaf(zz, wr[c + 256], a1);
  }
  atomicAdd(&hpre[b * 512 + c], a0);
  atomicAdd(&hpre[b * 512 + c + 256], a1);
}

// ---------------- lin2 + log_softmax ----------------
__global__ __launch_bounds__(128) void lin2_kernel(const float* __restrict__ hpre,
                                                   const float* __restrict__ l1b,
                                                   const float* __restrict__ W2,
                                                   const float* __restrict__ l2b,
                                                   float* __restrict__ out) {
  int b = blockIdx.x, tid = threadIdx.x;
  float a0 = 0.f, a1 = 0.f;
  for (int j = tid; j < 512; j += 128) {
    float t = fmaxf(hpre[b * 512 + j] + l1b[j], 0.f);
    a0 = fmaf(t, W2[j * 2 + 0], a0);
    a1 = fmaf(t, W2[j * 2 + 1], a1);
  }
#pragma unroll
  for (int s = 32; s > 0; s >>= 1) {
    a0 += __shfl_down(a0, s);
    a1 += __shfl_down(a1, s);
  }
  __shared__ float red[2][2];
  if ((tid & 63) == 0) { red[tid >> 6][0] = a0; red[tid >> 6][1] = a1; }
  __syncthreads();
  if (tid == 0) {
    float l0 = red[0][0] + red[1][0] + l2b[0];
    float l1 = red[0][1] + red[1][1] + l2b[1];
    float m = fmaxf(l0, l1);
    float lse = m + logf(expf(l0 - m) + expf(l1 - m));
    out[b * 2 + 0] = l0 - lse;
    out[b * 2 + 1] = l1 - lse;
  }
}

extern "C" void kernel_launch(void* const* d_in, const int* in_sizes, int n_in,
                              void* d_out, int out_size, void* d_ws, size_t ws_size,
                              hipStream_t stream) {
  const float* x   = (const float*)d_in[0];
  const int*   ei  = (const int*)d_in[2];
  const float* W1  = (const float*)d_in[3];
  const float* b1  = (const float*)d_in[4];
  const float* W2  = (const float*)d_in[5];
  const float* b2  = (const float*)d_in[6];
  const float* W3  = (const float*)d_in[7];
  const float* b3  = (const float*)d_in[8];
  const float* tkw = (const float*)d_in[9];
  const float* fcW = (const float*)d_in[10];
  const float* fcb = (const float*)d_in[11];
  const float* l1W = (const float*)d_in[12];
  const float* l1b = (const float*)d_in[13];
  const float* l2W = (const float*)d_in[14];
  const float* l2b = (const float*)d_in[15];
  float* out = (float*)d_out;

  char* ws = (char*)d_ws;
  size_t off = 0;
  auto alloc = [&](size_t bytes) {
    char* p = ws + off;
    off += (bytes + 255) & ~(size_t)255;
    return p;
  };
  // zero-init region (contiguous): cnt, fillc, gctr, hpre, hist
  int*   cnt   = (int*)alloc(15136 * 4);
  int*   fillc = (int*)alloc(15136 * 4);
  int*   gctr  = (int*)alloc(256);
  float* hpre  = (float*)alloc(4096 * 4);
  int*   hist  = (int*)alloc((size_t)BSZ * NBIN * 4);
  // --- end zero region ---
  int*   rowstart = (int*)alloc(15136 * 4);
  float* dinv  = (float*)alloc(15136 * 4);
  int4*  rowdesc = (int4*)alloc(15136 * 16);
  float* scal  = (float*)alloc(64);
  float* z     = (float*)alloc((size_t)BSZ * K_TOP * 4);
  float* score = (float*)alloc(121088 * 4);
  float* d2a   = (float*)alloc(121088 * 4);
  unsigned* keys = (unsigned*)alloc(121088 * 4);
  int*   suf   = (int*)alloc((size_t)BSZ * SUFS * 4);
  int2*  bucket = (int2*)alloc(121088 * 8);
  int2*  csr   = (int2*)alloc((size_t)E_N * 8);
  float* ax = (float*)alloc((size_t)BSZ * N_G * 64 * 4);
  float* hw = (float*)alloc((size_t)BSZ * N_G * NH * 4);
  float* h1 = (float*)alloc((size_t)BSZ * N_G * NH * 4);
  float* h2 = (float*)alloc((size_t)BSZ * N_G * NH * 4);
  (void)ws_size; (void)in_sizes; (void)n_in; (void)out_size;

  int zero_n = (int)(((char*)rowstart - (char*)cnt) / 4);
  zero_kernel<<<(zero_n + 1023) / 1024, 1024, 0, stream>>>(cnt, zero_n);
  count_kernel<<<(E_N + 255) / 256, 256, 0, stream>>>(ei, cnt);
  scan_kernel<<<(N_G + 1023) / 1024, 1024, 0, stream>>>(cnt, rowstart, dinv, rowdesc, gctr, tkw, scal);
  fill_kernel<<<(E_N + 255) / 256, 256, 0, stream>>>(ei, rowstart, dinv, fillc, csr);

  dim3 mmg(8 * 237);  // batch-pinned: b = blk&7
  int aggblocks = 8 * ((N_G + 3) / 4);

  // layer 1: agg(x) @ W1 (commutation)
  agg64_kernel<<<aggblocks, 256, 0, stream>>>(x, csr, rowdesc, ax);
  mm_kernel<64, true><<<mmg, 256, 0, stream>>>(ax, W1, b1, h1);
  // layer 2: full-width float2 aggregation
  mm_kernel<128, false><<<mmg, 256, 0, stream>>>(h1, W2, nullptr, hw);
  agg_f2_kernel<<<aggblocks, 256, 0, stream>>>(hw, csr, rowdesc, b2, h2);
  // layer 3: full-width agg fused with score/key/hist
  mm_kernel<128, false><<<mmg, 256, 0, stream>>>(h2, W3, nullptr, hw);
  agg_score_f2_kernel<<<aggblocks, 256, 0, stream>>>(hw, csr, rowdesc, b3, h1, h2,
                                                     tkw, fcW, scal, score, d2a, keys, hist);

  dim3 ng((N_G + 255) / 256, BSZ);
  suffix_kernel<<<BSZ, 1024, 0, stream>>>(hist, suf);
  scatter_kernel<<<ng, 256, 0, stream>>>(keys, hist, suf, bucket);
  rank_z_kernel<<<ng, 256, 0, stream>>>(keys, suf, bucket, score, d2a, fcb, z);

  dim3 l1g(32, BSZ);
  lin1_kernel<<<l1g, 256, 0, stream>>>(z, l1W, hpre);
  lin2_kernel<<<BSZ, 128, 0, stream>>>(hpre, l1b, l2W, l2b, out);
}